// Round 2
// baseline (9448.550 us; speedup 1.0000x reference)
//
#include <hip/hip_runtime.h>
#include <hip/hip_bf16.h>

// ---------------------------------------------------------------------------
// PerceptualLoss: conv1d x5 (+GroupNorm(1 group)+ReLU) -> Sinkhorn divergence
// Round 2: layer0 never materialized (fused into conv1); ws = 87.3 MiB.
// ---------------------------------------------------------------------------

#define EPS_SINK 0.0025f
#define INV_EPS_SINK 400.0f
#define EPS_LOG512 0.015595811562598769f

// ---- workspace layout (float offsets), total 22,872,576 floats = 87.3 MiB --
static const size_t O_H1    = 0ull;               // 16*512*1598 = 13,090,816
static const size_t O_H2    = 13090816ull;        // 16*512*798  =  6,537,216
static const size_t O_H3    = 0ull;               // 16*512*398 (reuses H1)
static const size_t O_FEATX = 19628032ull;        // 16*512*198  =  1,622,016
static const size_t O_FEATY = 21250048ull;
static const size_t O_STATS = 22872064ull;        // 512 floats
// aliased into H1/H2 region (dead once feats exist):
static const size_t O_CXY  = 0ull;
static const size_t O_CTXY = 4194304ull;
static const size_t O_CXX  = 8388608ull;
static const size_t O_CYY  = 12582912ull;
static const size_t O_AAX  = 16777216ull;
static const size_t O_AAY  = O_AAX + 8192ull;
static const size_t O_F    = O_AAY + 8192ull;     // 3*16*512
static const size_t O_G    = O_F + 24576ull;      // 3*16*512

// ---------------------------------------------------------------------------
// conv0_stats: per-batch sum/sumsq of RAW conv0 output (no store).
// conv0: 1 in-channel, k=10, s=5; out length 6399.
// ---------------------------------------------------------------------------
__global__ __launch_bounds__(256) void conv0_stats(
    const float* __restrict__ wav, const float* __restrict__ W0,
    float* __restrict__ stats)
{
    __shared__ float LW[5120];
    __shared__ float red[2][256];
    const int tid = threadIdx.x;
    for (int e = tid; e < 5120; e += 256) LW[e] = W0[e];

    const int b = blockIdx.y;
    const int t = blockIdx.x * 256 + tid;
    const bool valid = (t < 6399);
    float xv[10];
#pragma unroll
    for (int d = 0; d < 10; ++d) xv[d] = 0.f;
    if (valid) {
        const float* wp = wav + (size_t)b * 32000 + (size_t)t * 5;
#pragma unroll
        for (int d = 0; d < 10; ++d) xv[d] = wp[d];
    }
    __syncthreads();

    float lsum = 0.f, lsq = 0.f;
    for (int oc = 0; oc < 512; ++oc) {
        float a = 0.f;
#pragma unroll
        for (int d = 0; d < 10; ++d) a += LW[oc * 10 + d] * xv[d];
        if (valid) { lsum += a; lsq += a * a; }
    }
    red[0][tid] = lsum; red[1][tid] = lsq;
    __syncthreads();
    for (int s2 = 128; s2 > 0; s2 >>= 1) {
        if (tid < s2) { red[0][tid] += red[0][tid + s2]; red[1][tid] += red[1][tid + s2]; }
        __syncthreads();
    }
    if (tid == 0) {
        atomicAdd(&stats[2 * b], red[0][0]);
        atomicAdd(&stats[2 * b + 1], red[1][0]);
    }
}

// ---------------------------------------------------------------------------
// conv1_fused: layer1 raw output directly from wav. Recomputes conv0 +
// GroupNorm(stats0) + ReLU inline while staging the LX tile.
// K=8, S=4; Lin(h0)=6399, Lout=1598.  64oc x 64t tile, 256 threads.
// Fused GroupNorm stats accumulation on raw layer1 outputs.
// ---------------------------------------------------------------------------
__global__ __launch_bounds__(256) void conv1_fused(
    const float* __restrict__ wav, const float* __restrict__ W0,
    const float* __restrict__ g0, const float* __restrict__ b0,
    const float* __restrict__ stats0, const float* __restrict__ W1,
    float* __restrict__ out, float* __restrict__ stats1)
{
    constexpr int K = 8, S = 4;
    constexpr int SPAN = 64 * S + K - S;          // 260 h0 samples
    constexpr int WSPAN = (SPAN - 1) * 5 + 10;    // 1305 wav samples
    __shared__ __align__(16) float LW[8 * K][68]; // W1 tile [ic*K+dt][oc]
    __shared__ __align__(16) float LX[8][S][68];  // normed h0 (phase-split)
    __shared__ float LWAV[1312];
    __shared__ float LW0[8][10];
    __shared__ float LSC[8], LSH[8];
    __shared__ float red[2][256];

    const int tid = threadIdx.x;
    const int tx = tid & 15, ty = tid >> 4;
    const int b   = blockIdx.z;
    const int ocb = blockIdx.y * 64;
    const int t0  = blockIdx.x * 64;

    const float invN0 = 1.f / (512.f * 6399.f);
    const float mu = stats0[2 * b] * invN0;
    const float var = stats0[2 * b + 1] * invN0 - mu * mu;
    const float rs = rsqrtf(var + 1e-5f);

    // stage wav span once
    const int w0 = t0 * 20;   // t0*S*5
    const float* wb = wav + (size_t)b * 32000;
    for (int e = tid; e < WSPAN; e += 256) {
        const int gw = w0 + e;
        LWAV[e] = (gw < 32000) ? wb[gw] : 0.f;
    }

    float acc[4][4];
#pragma unroll
    for (int q = 0; q < 4; ++q)
#pragma unroll
        for (int p = 0; p < 4; ++p) acc[q][p] = 0.f;

    for (int ic0 = 0; ic0 < 512; ic0 += 8) {
        __syncthreads();  // protect prior iter's LX/LW reads (and LWAV first use)
        // --- stage A: W1 tile, W0 chunk, per-ic norm scalars
#pragma unroll
        for (int r = 0; r < (64 * 8 * K) / 256; ++r) {
            const int e = tid + r * 256;
            const int oc = e / (8 * K);
            const int idx = e % (8 * K);
            const int ic = idx / K, dt = idx % K;
            LW[idx][oc] = W1[((size_t)(ocb + oc) * 512 + (size_t)(ic0 + ic)) * K + dt];
        }
        if (tid < 80) LW0[tid / 10][tid % 10] = W0[ic0 * 10 + tid];
        if (tid < 8) {
            const float sc = rs * g0[ic0 + tid];
            LSC[tid] = sc;
            LSH[tid] = b0[ic0 + tid] - mu * sc;
        }
        __syncthreads();
        // --- stage B: build LX = relu(norm(conv0)) over the span
        for (int e = tid; e < 8 * SPAN; e += 256) {
            const int ic = e / SPAN, j = e % SPAN;
            const int gj = t0 * S + j;
            float v = 0.f;
            if (gj < 6399) {
                float raw = 0.f;
#pragma unroll
                for (int d = 0; d < 10; ++d) raw += LW0[ic][d] * LWAV[j * 5 + d];
                v = fmaxf(raw * LSC[ic] + LSH[ic], 0.f);
            }
            LX[ic][j % S][j / S] = v;
        }
        __syncthreads();
        // --- compute
#pragma unroll
        for (int ic = 0; ic < 8; ++ic) {
            float xv[S][5];
#pragma unroll
            for (int ph = 0; ph < S; ++ph) {
                const float4 v4 = *(const float4*)&LX[ic][ph][tx * 4];
                xv[ph][0] = v4.x; xv[ph][1] = v4.y; xv[ph][2] = v4.z; xv[ph][3] = v4.w;
                xv[ph][4] = LX[ic][ph][tx * 4 + 4];
            }
#pragma unroll
            for (int dt = 0; dt < K; ++dt) {
                const int ph = dt & (S - 1);
                const int off = dt / S;
                const float4 w4 = *(const float4*)&LW[ic * K + dt][ty * 4];
                const float w[4] = {w4.x, w4.y, w4.z, w4.w};
#pragma unroll
                for (int q = 0; q < 4; ++q)
#pragma unroll
                    for (int p = 0; p < 4; ++p)
                        acc[q][p] += w[q] * xv[ph][off + p];
            }
        }
    }

    // --- epilogue: store raw layer1 + accumulate stats1
    float lsum = 0.f, lsq = 0.f;
#pragma unroll
    for (int q = 0; q < 4; ++q) {
        const int oc = ocb + ty * 4 + q;
        float* orow = out + ((size_t)b * 512 + oc) * 1598ull;
#pragma unroll
        for (int p = 0; p < 4; ++p) {
            const int t = t0 + tx * 4 + p;
            if (t < 1598) {
                const float v = acc[q][p];
                orow[t] = v;
                lsum += v; lsq += v * v;
            }
        }
    }
    __syncthreads();
    red[0][tid] = lsum; red[1][tid] = lsq;
    __syncthreads();
    for (int s2 = 128; s2 > 0; s2 >>= 1) {
        if (tid < s2) { red[0][tid] += red[0][tid + s2]; red[1][tid] += red[1][tid + s2]; }
        __syncthreads();
    }
    if (tid == 0) {
        atomicAdd(&stats1[2 * b], red[0][0]);
        atomicAdd(&stats1[2 * b + 1], red[1][0]);
    }
}

// ---------------------------------------------------------------------------
// Generic conv (512 -> 512 channels), k=4, s=2.
// Tile: 64 oc x 64 t, 256 threads, each thread 4oc x 4t. Fused GN stats.
// ---------------------------------------------------------------------------
template <int K, int S>
__global__ __launch_bounds__(256) void conv_gn(
    const float* __restrict__ x, const float* __restrict__ W,
    float* __restrict__ out, float* __restrict__ stats,
    int Lin, int Lout)
{
    constexpr int SPAN = 64 * S + K - S;
    __shared__ __align__(16) float LW[8 * K][68];
    __shared__ __align__(16) float LX[8][S][68];
    __shared__ float red[2][256];

    const int tid = threadIdx.x;
    const int tx = tid & 15, ty = tid >> 4;
    const int b   = blockIdx.z;
    const int ocb = blockIdx.y * 64;
    const int t0  = blockIdx.x * 64;

    float acc[4][4];
#pragma unroll
    for (int q = 0; q < 4; ++q)
#pragma unroll
        for (int p = 0; p < 4; ++p) acc[q][p] = 0.f;

    const float* xb = x + (size_t)b * 512 * Lin;

    for (int ic0 = 0; ic0 < 512; ic0 += 8) {
#pragma unroll
        for (int r = 0; r < (64 * 8 * K) / 256; ++r) {
            const int e = tid + r * 256;
            const int oc = e / (8 * K);
            const int idx = e % (8 * K);
            const int ic = idx / K, dt = idx % K;
            LW[idx][oc] = W[((size_t)(ocb + oc) * 512 + (size_t)(ic0 + ic)) * K + dt];
        }
        for (int e = tid; e < 8 * SPAN; e += 256) {
            const int ic = e / SPAN, j = e % SPAN;
            const int gj = t0 * S + j;
            float v = 0.f;
            if (gj < Lin) v = xb[(size_t)(ic0 + ic) * Lin + gj];
            LX[ic][j % S][j / S] = v;
        }
        __syncthreads();

#pragma unroll
        for (int ic = 0; ic < 8; ++ic) {
            float xv[S][5];
#pragma unroll
            for (int ph = 0; ph < S; ++ph) {
                const float4 v4 = *(const float4*)&LX[ic][ph][tx * 4];
                xv[ph][0] = v4.x; xv[ph][1] = v4.y; xv[ph][2] = v4.z; xv[ph][3] = v4.w;
                xv[ph][4] = LX[ic][ph][tx * 4 + 4];
            }
#pragma unroll
            for (int dt = 0; dt < K; ++dt) {
                const int ph = dt & (S - 1);
                const int off = dt / S;
                const float4 w4 = *(const float4*)&LW[ic * K + dt][ty * 4];
                const float w[4] = {w4.x, w4.y, w4.z, w4.w};
#pragma unroll
                for (int q = 0; q < 4; ++q)
#pragma unroll
                    for (int p = 0; p < 4; ++p)
                        acc[q][p] += w[q] * xv[ph][off + p];
            }
        }
        __syncthreads();
    }

    float lsum = 0.f, lsq = 0.f;
#pragma unroll
    for (int q = 0; q < 4; ++q) {
        const int oc = ocb + ty * 4 + q;
        float* orow = out + ((size_t)b * 512 + oc) * (size_t)Lout;
#pragma unroll
        for (int p = 0; p < 4; ++p) {
            const int t = t0 + tx * 4 + p;
            if (t < Lout) {
                const float v = acc[q][p];
                orow[t] = v;
                lsum += v; lsq += v * v;
            }
        }
    }
    red[0][tid] = lsum; red[1][tid] = lsq;
    __syncthreads();
    for (int s2 = 128; s2 > 0; s2 >>= 1) {
        if (tid < s2) { red[0][tid] += red[0][tid + s2]; red[1][tid] += red[1][tid + s2]; }
        __syncthreads();
    }
    if (tid == 0) {
        atomicAdd(&stats[2 * b], red[0][0]);
        atomicAdd(&stats[2 * b + 1], red[1][0]);
    }
}

// ---------------------------------------------------------------------------
// GroupNorm(1 group) + affine + ReLU, in place.
// ---------------------------------------------------------------------------
__global__ __launch_bounds__(256) void norm_relu(
    float* __restrict__ h, const float* __restrict__ stats,
    const float* __restrict__ gamma, const float* __restrict__ beta,
    int L, float invN)
{
    const int row = blockIdx.y;           // b*512 + oc
    const int b = row >> 9, oc = row & 511;
    const int t = blockIdx.x * 256 + threadIdx.x;
    if (t >= L) return;
    const float mu = stats[2 * b] * invN;
    const float var = stats[2 * b + 1] * invN - mu * mu;
    const float rs = rsqrtf(var + 1e-5f);
    const float sc = rs * gamma[oc];
    const float sh = beta[oc] - mu * sc;
    const size_t i = (size_t)row * L + t;
    const float v = h[i] * sc + sh;
    h[i] = v > 0.f ? v : 0.f;
}

// ---------------------------------------------------------------------------
// Row squared-norms of features (16,512,198): one wave per row.
// ---------------------------------------------------------------------------
__global__ __launch_bounds__(256) void aa_kernel(
    const float* __restrict__ fX, const float* __restrict__ fY,
    float* __restrict__ aaX, float* __restrict__ aaY)
{
    const int wave = threadIdx.x >> 6, lane = threadIdx.x & 63;
    const int R = blockIdx.x * 4 + wave;          // 0..16383
    const float* f = (R < 8192) ? fX : fY;
    const int r = R & 8191;
    const float* row = f + (size_t)r * 198;
    float s = 0.f;
#pragma unroll
    for (int k = 0; k < 4; ++k) {
        const int j = lane + 64 * k;
        if (j < 198) { const float v = row[j]; s += v * v; }
    }
#pragma unroll
    for (int off = 32; off > 0; off >>= 1) s += __shfl_xor(s, off);
    if (lane == 0) ((R < 8192) ? aaX : aaY)[r] = s;
}

// ---------------------------------------------------------------------------
// Cost matrices: C[b,n,m] = 0.5*max(aa[n]+bb[m]-2<p_n,q_m>, 0), D=198.
// ---------------------------------------------------------------------------
__global__ __launch_bounds__(256) void cost_kernel(
    const float* __restrict__ fX, const float* __restrict__ fY,
    const float* __restrict__ aaX, const float* __restrict__ aaY,
    float* __restrict__ Cxy, float* __restrict__ Cxx, float* __restrict__ Cyy,
    float* __restrict__ CTxy)
{
    const int z = blockIdx.z;
    const int mat = z >> 4, b = z & 15;
    const float *P, *Q, *aP, *aQ;
    float *Cm, *CT = nullptr;
    if (mat == 0) { P = fX; Q = fY; aP = aaX; aQ = aaY; Cm = Cxy; CT = CTxy; }
    else if (mat == 1) { P = fX; Q = fX; aP = aaX; aQ = aaX; Cm = Cxx; }
    else { P = fY; Q = fY; aP = aaY; aQ = aaY; Cm = Cyy; }

    const int n0 = blockIdx.x * 32, m0 = blockIdx.y * 32;
    __shared__ float LP[32][201], LQ[32][201];
    const int tid = threadIdx.x;
    for (int e = tid; e < 32 * 198; e += 256) {
        const int r = e / 198, d = e % 198;
        LP[r][d] = P[((size_t)b * 512 + n0 + r) * 198 + d];
        LQ[r][d] = Q[((size_t)b * 512 + m0 + r) * 198 + d];
    }
    __syncthreads();

    const int tx = tid & 31, ty = tid >> 5;
    float dot[4] = {0.f, 0.f, 0.f, 0.f};
    for (int d = 0; d < 198; ++d) {
        const float qv = LQ[tx][d];
#pragma unroll
        for (int q = 0; q < 4; ++q) dot[q] += LP[ty + 8 * q][d] * qv;
    }
    const int m = m0 + tx;
    const float bbm = aQ[b * 512 + m];
#pragma unroll
    for (int q = 0; q < 4; ++q) {
        const int n = n0 + ty + 8 * q;
        const float c = 0.5f * fmaxf(aP[b * 512 + n] + bbm - 2.f * dot[q], 0.f);
        Cm[((size_t)b * 512 + n) * 512 + m] = c;
        if (CT) CT[((size_t)b * 512 + m) * 512 + n] = c;
    }
}

// ---------------------------------------------------------------------------
// One Sinkhorn half-update: dst[i] = eps*log512 - eps*LSE_j((src[j]-M[i,j])/eps)
// ---------------------------------------------------------------------------
__global__ __launch_bounds__(256) void sink_update(
    float* __restrict__ dst, const float* __restrict__ src,
    const float* __restrict__ M0, const float* __restrict__ M1,
    const float* __restrict__ M2)
{
    const int p = blockIdx.y;
    const int mat = p >> 4, b = p & 15;
    const float* M = (mat == 0) ? M0 : ((mat == 1) ? M1 : M2);
    const float* sp = src + (size_t)p * 512;
    __shared__ float sf[512];
    const int tid = threadIdx.x;
    sf[tid] = sp[tid] * INV_EPS_SINK;
    sf[tid + 256] = sp[tid + 256] * INV_EPS_SINK;
    __syncthreads();

    const int wave = tid >> 6, lane = tid & 63;
    const int i = blockIdx.x * 4 + wave;
    const float* row = M + ((size_t)b * 512 + i) * 512;

    float mx = -3.4e38f, ss = 0.f;
#pragma unroll
    for (int k = 0; k < 8; ++k) {
        const int j = lane + k * 64;
        const float arg = sf[j] - row[j] * INV_EPS_SINK;
        const float nm = fmaxf(mx, arg);
        ss = ss * __expf(mx - nm) + __expf(arg - nm);
        mx = nm;
    }
#pragma unroll
    for (int off = 32; off > 0; off >>= 1) {
        const float om = __shfl_xor(mx, off);
        const float os = __shfl_xor(ss, off);
        const float nm = fmaxf(mx, om);
        ss = ss * __expf(mx - nm) + os * __expf(om - nm);
        mx = nm;
    }
    if (lane == 0)
        dst[(size_t)p * 512 + i] = EPS_LOG512 - EPS_SINK * (mx + logf(ss));
}

// ---------------------------------------------------------------------------
// Final: out[b] = mean(f_xy+g_xy) - 0.5*mean(f_xx+g_xx) - 0.5*mean(f_yy+g_yy)
// ---------------------------------------------------------------------------
__global__ __launch_bounds__(256) void final_kernel(
    const float* __restrict__ f, const float* __restrict__ g,
    float* __restrict__ out)
{
    const int b = blockIdx.x, tid = threadIdx.x;
    __shared__ float red[256];
    float a = 0.f;
    for (int n = tid; n < 512; n += 256) {
        const float xy = f[(0 * 16 + b) * 512 + n] + g[(0 * 16 + b) * 512 + n];
        const float xx = f[(1 * 16 + b) * 512 + n] + g[(1 * 16 + b) * 512 + n];
        const float yy = f[(2 * 16 + b) * 512 + n] + g[(2 * 16 + b) * 512 + n];
        a += xy - 0.5f * (xx + yy);
    }
    red[tid] = a;
    __syncthreads();
    for (int s2 = 128; s2 > 0; s2 >>= 1) {
        if (tid < s2) red[tid] += red[tid + s2];
        __syncthreads();
    }
    if (tid == 0) out[b] = red[0] * (1.0f / 512.0f);
}

// ---------------------------------------------------------------------------
extern "C" void kernel_launch(void* const* d_in, const int* in_sizes, int n_in,
                              void* d_out, int out_size, void* d_ws, size_t ws_size,
                              hipStream_t stream)
{
    (void)in_sizes; (void)n_in; (void)out_size; (void)ws_size;
    float* ws = (float*)d_ws;
    const float* yhat = (const float*)d_in[0];
    const float* ysig = (const float*)d_in[1];
    const float* Wl[5]; const float* gl[5]; const float* bl[5];
    for (int i = 0; i < 5; ++i) {
        Wl[i] = (const float*)d_in[2 + 3 * i];
        gl[i] = (const float*)d_in[3 + 3 * i];
        bl[i] = (const float*)d_in[4 + 3 * i];
    }
    float* out = (float*)d_out;

    hipMemsetAsync(ws + O_STATS, 0, 512 * sizeof(float), stream);

    for (int s = 0; s < 2; ++s) {
        const float* wav = (s == 0) ? yhat : ysig;
        float* stats = ws + O_STATS + (size_t)s * 160;
        float* h1 = ws + O_H1;
        float* h2 = ws + O_H2;
        float* h3 = ws + O_H3;     // reuses H1 (layer1 dead after layer2)
        float* ft = ws + ((s == 0) ? O_FEATX : O_FEATY);

        conv0_stats<<<dim3(25, 16), 256, 0, stream>>>(wav, Wl[0], stats);

        conv1_fused<<<dim3(25, 8, 16), 256, 0, stream>>>(
            wav, Wl[0], gl[0], bl[0], stats, Wl[1], h1, stats + 32);
        norm_relu<<<dim3(7, 8192), 256, 0, stream>>>(h1, stats + 32, gl[1], bl[1], 1598, 1.f / (512.f * 1598.f));

        conv_gn<4, 2><<<dim3(13, 8, 16), 256, 0, stream>>>(h1, Wl[2], h2, stats + 64, 1598, 798);
        norm_relu<<<dim3(4, 8192), 256, 0, stream>>>(h2, stats + 64, gl[2], bl[2], 798, 1.f / (512.f * 798.f));

        conv_gn<4, 2><<<dim3(7, 8, 16), 256, 0, stream>>>(h2, Wl[3], h3, stats + 96, 798, 398);
        norm_relu<<<dim3(2, 8192), 256, 0, stream>>>(h3, stats + 96, gl[3], bl[3], 398, 1.f / (512.f * 398.f));

        conv_gn<4, 2><<<dim3(4, 8, 16), 256, 0, stream>>>(h3, Wl[4], ft, stats + 128, 398, 198);
        norm_relu<<<dim3(1, 8192), 256, 0, stream>>>(ft, stats + 128, gl[4], bl[4], 198, 1.f / (512.f * 198.f));
    }

    aa_kernel<<<4096, 256, 0, stream>>>(ws + O_FEATX, ws + O_FEATY, ws + O_AAX, ws + O_AAY);
    cost_kernel<<<dim3(16, 16, 48), 256, 0, stream>>>(
        ws + O_FEATX, ws + O_FEATY, ws + O_AAX, ws + O_AAY,
        ws + O_CXY, ws + O_CXX, ws + O_CYY, ws + O_CTXY);

    hipMemsetAsync(ws + O_F, 0, 24576 * sizeof(float), stream);

    for (int it = 0; it < 50; ++it) {
        sink_update<<<dim3(128, 48), 256, 0, stream>>>(
            ws + O_G, ws + O_F, ws + O_CTXY, ws + O_CXX, ws + O_CYY);
        sink_update<<<dim3(128, 48), 256, 0, stream>>>(
            ws + O_F, ws + O_G, ws + O_CXY, ws + O_CXX, ws + O_CYY);
    }

    final_kernel<<<16, 256, 0, stream>>>(ws + O_F, ws + O_G, out);
}

// Round 3
// 4436.168 us; speedup vs baseline: 2.1299x; 2.1299x over previous
//
#include <hip/hip_runtime.h>

typedef unsigned int uint;
typedef unsigned short ushort;
using short4v = __attribute__((ext_vector_type(4))) short;
using short8v = __attribute__((ext_vector_type(8))) short;
using float4v = __attribute__((ext_vector_type(4))) float;

#define EPS_SINK 0.0025f
#define INV_EPS_SINK 400.0f
#define EPS_LOG512 0.015595811562598769f

// ---- workspace layout (BYTE offsets), total 91,490,304 bytes ----
static const size_t O_H1HI  = 0ull;           // 16*512*1598 ushort = 26,181,632
static const size_t O_H1LO  = 26181632ull;
static const size_t O_H2HI  = 52363264ull;    // 16*512*798 ushort = 13,074,432
static const size_t O_H2LO  = 65437696ull;
static const size_t O_H3HI  = 0ull;           // alias (h1 dead) 6,520,832
static const size_t O_H3LO  = 6520832ull;
static const size_t O_FEATX = 78512128ull;    // 16*512*198 fp32 = 6,488,064
static const size_t O_FEATY = 85000192ull;
static const size_t O_STATS = 91488256ull;    // 512 floats
// aliased into h1/h2 after convs:
static const size_t O_CXY  = 0ull;
static const size_t O_CTXY = 16777216ull;
static const size_t O_CXX  = 33554432ull;
static const size_t O_CYY  = 50331648ull;
static const size_t O_AAX  = 67108864ull;
static const size_t O_AAY  = 67141632ull;
static const size_t O_F    = 67174400ull;     // 3*16*512 fp32
static const size_t O_G    = 67272704ull;

// ---- bf16 helpers (RNE) ----
static __device__ __forceinline__ ushort f2bf(float f) {
    union { float f; uint u; } c; c.f = f;
    return (ushort)((c.u + 0x7FFFu + ((c.u >> 16) & 1u)) >> 16);
}
static __device__ __forceinline__ float b2f(ushort h) {
    union { uint u; float f; } c; c.u = ((uint)h) << 16;
    return c.f;
}

// ---------------------------------------------------------------------------
// conv0_stats: per-batch sum/sumsq of RAW conv0 output (k=10,s=5), no store.
// ---------------------------------------------------------------------------
__global__ __launch_bounds__(256) void conv0_stats(
    const float* __restrict__ wav, const float* __restrict__ W0,
    float* __restrict__ stats)
{
    __shared__ float LW[5120];
    __shared__ float red[2][256];
    const int tid = threadIdx.x;
    for (int e = tid; e < 5120; e += 256) LW[e] = W0[e];

    const int b = blockIdx.y;
    const int t = blockIdx.x * 256 + tid;
    const bool valid = (t < 6399);
    float xv[10];
#pragma unroll
    for (int d = 0; d < 10; ++d) xv[d] = 0.f;
    if (valid) {
        const float* wp = wav + (size_t)b * 32000 + (size_t)t * 5;
#pragma unroll
        for (int d = 0; d < 10; ++d) xv[d] = wp[d];
    }
    __syncthreads();

    float lsum = 0.f, lsq = 0.f;
    for (int oc = 0; oc < 512; ++oc) {
        float a = 0.f;
#pragma unroll
        for (int d = 0; d < 10; ++d) a += LW[oc * 10 + d] * xv[d];
        if (valid) { lsum += a; lsq += a * a; }
    }
    red[0][tid] = lsum; red[1][tid] = lsq;
    __syncthreads();
    for (int s2 = 128; s2 > 0; s2 >>= 1) {
        if (tid < s2) { red[0][tid] += red[0][tid + s2]; red[1][tid] += red[1][tid + s2]; }
        __syncthreads();
    }
    if (tid == 0) {
        atomicAdd(&stats[2 * b], red[0][0]);
        atomicAdd(&stats[2 * b + 1], red[1][0]);
    }
}

// ---------------------------------------------------------------------------
// conv1_mfma: layer1 (K=8,S=4, 512ic) from wav, recomputing h0 = relu(GN(conv0))
// into LDS as bf16 hi/lo. MFMA 16x16x32_bf16, compensated hi/lo (3 products).
// Output: pair-interleaved bf16 hi/lo [b][256 pairs][1598][2] + GN stats.
// ---------------------------------------------------------------------------
__global__ __launch_bounds__(256) void conv1_mfma(
    const float* __restrict__ wav, const float* __restrict__ W0,
    const float* __restrict__ g0, const float* __restrict__ b0,
    const float* __restrict__ stats0, const float* __restrict__ W1,
    ushort* __restrict__ ohi, ushort* __restrict__ olo,
    float* __restrict__ stats1)
{
    __shared__ float LWAV[1312];
    __shared__ float LW0[8][10];
    __shared__ float LSC[8], LSH[8];
    __shared__ ushort LWhi[2][64][40], LWlo[2][64][40];   // [k32l][oc][k(32)+pad]
    __shared__ ushort LXhi[8][264], LXlo[8][264];         // [ic][sample]
    __shared__ float red[2][256];

    const int tid  = threadIdx.x;
    const int lane = tid & 63, wv = tid >> 6;
    const int m    = lane & 15, quad = lane >> 4;
    const int mt2  = wv >> 1, nt2 = wv & 1;
    const int b    = blockIdx.z;
    const int ocb  = blockIdx.y * 64;
    const int t0   = blockIdx.x * 64;
    const int Lout = 1598;

    const float invN0 = 1.f / (512.f * 6399.f);
    const float mu = stats0[2 * b] * invN0;
    const float var = stats0[2 * b + 1] * invN0 - mu * mu;
    const float rs = rsqrtf(var + 1e-5f);

    // stage wav span once: wav[t0*20 + 0..1304]
    const float* wb = wav + (size_t)b * 32000;
    const int w0 = t0 * 20;
    for (int e = tid; e < 1305; e += 256) {
        const int gw = w0 + e;
        LWAV[e] = (gw < 32000) ? wb[gw] : 0.f;
    }

    float4v acc[2][2];
#pragma unroll
    for (int i = 0; i < 2; ++i)
#pragma unroll
        for (int j = 0; j < 2; ++j) acc[i][j] = (float4v){0.f, 0.f, 0.f, 0.f};

    for (int ic0 = 0; ic0 < 512; ic0 += 8) {
        __syncthreads();
        // --- stage W1 chunk: 512 frag-units (k32l, oc, q), ic = ic0+k32l*4+q
#pragma unroll
        for (int r = 0; r < 2; ++r) {
            const int e = tid + r * 256;
            const int k32l = e >> 8, oc = (e >> 2) & 63, q = e & 3;
            const int ic = ic0 + k32l * 4 + q;
            const float4* wp = (const float4*)(W1 + (((size_t)(ocb + oc) * 512 + ic) * 8));
            const float4 a = wp[0], c = wp[1];
            float v[8] = {a.x, a.y, a.z, a.w, c.x, c.y, c.z, c.w};
            short8v hi8, lo8;
#pragma unroll
            for (int k = 0; k < 8; ++k) {
                const ushort h = f2bf(v[k]);
                hi8[k] = (short)h;
                lo8[k] = (short)f2bf(v[k] - b2f(h));
            }
            *(short8v*)&LWhi[k32l][oc][q * 8] = hi8;
            *(short8v*)&LWlo[k32l][oc][q * 8] = lo8;
        }
        if (tid < 80) LW0[tid / 10][tid % 10] = W0[ic0 * 10 + tid];
        if (tid < 8) {
            const float sc = rs * g0[ic0 + tid];
            LSC[tid] = sc;
            LSH[tid] = b0[ic0 + tid] - mu * sc;
        }
        __syncthreads();
        // --- recompute h0 chunk into LX (8 ic x 260 samples)
        for (int e = tid; e < 2080; e += 256) {
            const int ic = e / 260, j = e - ic * 260;
            const int gj = t0 * 4 + j;
            float v = 0.f;
            if (gj < 6399) {
                float raw = 0.f;
#pragma unroll
                for (int d = 0; d < 10; ++d) raw += LW0[ic][d] * LWAV[j * 5 + d];
                v = fmaxf(raw * LSC[ic] + LSH[ic], 0.f);
            }
            const ushort h = f2bf(v);
            LXhi[ic][j] = h;
            LXlo[ic][j] = f2bf(v - b2f(h));
        }
        __syncthreads();
        // --- compute: 2 K-steps of 32
#pragma unroll
        for (int k32l = 0; k32l < 2; ++k32l) {
            short8v ahi[2], alo[2], bhi[2], blo[2];
#pragma unroll
            for (int i = 0; i < 2; ++i) {
                const int ocl = (mt2 * 2 + i) * 16 + m;
                ahi[i] = *(const short8v*)&LWhi[k32l][ocl][quad * 8];
                alo[i] = *(const short8v*)&LWlo[k32l][ocl][quad * 8];
            }
#pragma unroll
            for (int j = 0; j < 2; ++j) {
                const int tl = (nt2 * 2 + j) * 16 + m;
                const int icl = k32l * 4 + quad;
                const short4v h0a = *(const short4v*)&LXhi[icl][tl * 4];
                const short4v h0b = *(const short4v*)&LXhi[icl][tl * 4 + 4];
                const short4v l0a = *(const short4v*)&LXlo[icl][tl * 4];
                const short4v l0b = *(const short4v*)&LXlo[icl][tl * 4 + 4];
                bhi[j] = __builtin_shufflevector(h0a, h0b, 0, 1, 2, 3, 4, 5, 6, 7);
                blo[j] = __builtin_shufflevector(l0a, l0b, 0, 1, 2, 3, 4, 5, 6, 7);
            }
#pragma unroll
            for (int i = 0; i < 2; ++i)
#pragma unroll
                for (int j = 0; j < 2; ++j) {
                    acc[i][j] = __builtin_amdgcn_mfma_f32_16x16x32_bf16(ahi[i], bhi[j], acc[i][j], 0, 0, 0);
                    acc[i][j] = __builtin_amdgcn_mfma_f32_16x16x32_bf16(ahi[i], blo[j], acc[i][j], 0, 0, 0);
                    acc[i][j] = __builtin_amdgcn_mfma_f32_16x16x32_bf16(alo[i], bhi[j], acc[i][j], 0, 0, 0);
                }
        }
    }

    // --- epilogue: pair-interleaved bf16 store + stats
    float lsum = 0.f, lsq = 0.f;
    uint* ohiU = (uint*)ohi;
    uint* oloU = (uint*)olo;
#pragma unroll
    for (int i = 0; i < 2; ++i) {
        const int ocb2 = ocb + (mt2 * 2 + i) * 16 + quad * 4;
#pragma unroll
        for (int j = 0; j < 2; ++j) {
            const int t = t0 + (nt2 * 2 + j) * 16 + m;
            if (t < Lout) {
#pragma unroll
                for (int pr = 0; pr < 2; ++pr) {
                    const float v0 = acc[i][j][pr * 2], v1 = acc[i][j][pr * 2 + 1];
                    const ushort h0 = f2bf(v0), h1 = f2bf(v1);
                    const ushort q0 = f2bf(v0 - b2f(h0)), q1 = f2bf(v1 - b2f(h1));
                    const uint p = (uint)((ocb2 >> 1) + pr);
                    const size_t uidx = ((size_t)(b * 256 + p)) * Lout + t;
                    ohiU[uidx] = (uint)h0 | ((uint)h1 << 16);
                    oloU[uidx] = (uint)q0 | ((uint)q1 << 16);
                    lsum += v0 + v1; lsq += v0 * v0 + v1 * v1;
                }
            }
        }
    }
    __syncthreads();
    red[0][tid] = lsum; red[1][tid] = lsq;
    __syncthreads();
    for (int s2 = 128; s2 > 0; s2 >>= 1) {
        if (tid < s2) { red[0][tid] += red[0][tid + s2]; red[1][tid] += red[1][tid + s2]; }
        __syncthreads();
    }
    if (tid == 0) {
        atomicAdd(&stats1[2 * b], red[0][0]);
        atomicAdd(&stats1[2 * b + 1], red[1][0]);
    }
}

// ---------------------------------------------------------------------------
// conv_mfma: layers 2-4 (K=4,S=2, 512ic). Input pair-interleaved bf16 hi/lo.
// PAIRED: writes pair-interleaved bf16 hi/lo; else plain fp32 [b][512][Lout].
// ---------------------------------------------------------------------------
template <bool PAIRED>
__global__ __launch_bounds__(256) void conv_mfma(
    const ushort* __restrict__ xhi, const ushort* __restrict__ xlo,
    const float* __restrict__ W,
    ushort* __restrict__ ohi, ushort* __restrict__ olo,
    float* __restrict__ oplain,
    float* __restrict__ stats, int Lin, int Lout)
{
    __shared__ ushort LWhi[2][64][40], LWlo[2][64][40];
    __shared__ ushort LXhi[8][136][2], LXlo[8][136][2];   // [icpair][sample][member]
    __shared__ float red[2][256];

    const int tid  = threadIdx.x;
    const int lane = tid & 63, wv = tid >> 6;
    const int m    = lane & 15, quad = lane >> 4;
    const int mt2  = wv >> 1, nt2 = wv & 1;
    const int b    = blockIdx.z;
    const int ocb  = blockIdx.y * 64;
    const int t0   = blockIdx.x * 64;

    float4v acc[2][2];
#pragma unroll
    for (int i = 0; i < 2; ++i)
#pragma unroll
        for (int j = 0; j < 2; ++j) acc[i][j] = (float4v){0.f, 0.f, 0.f, 0.f};

    const int lim = (Lin - t0 * 2) * 2;   // valid ushorts in a pair-row slice

    for (int ic0 = 0; ic0 < 512; ic0 += 16) {
        __syncthreads();
        // --- stage W chunk: 512 frag-units (k32l, oc, q); ic pair = ic0+k32l*8+2q
#pragma unroll
        for (int r = 0; r < 2; ++r) {
            const int e = tid + r * 256;
            const int k32l = e >> 8, oc = (e >> 2) & 63, q = e & 3;
            const int icA = ic0 + k32l * 8 + 2 * q;
            const float4 a = *(const float4*)(W + (((size_t)(ocb + oc) * 512 + icA) * 4));
            const float4 c = *(const float4*)(W + (((size_t)(ocb + oc) * 512 + icA + 1) * 4));
            float v[8] = {a.x, c.x, a.y, c.y, a.z, c.z, a.w, c.w};  // interleave A,B per dt
            short8v hi8, lo8;
#pragma unroll
            for (int k = 0; k < 8; ++k) {
                const ushort h = f2bf(v[k]);
                hi8[k] = (short)h;
                lo8[k] = (short)f2bf(v[k] - b2f(h));
            }
            *(short8v*)&LWhi[k32l][oc][q * 8] = hi8;
            *(short8v*)&LWlo[k32l][oc][q * 8] = lo8;
        }
        // --- stage X: 8 pair-rows x 33 16B-units x 2 sel = 528 units
        for (int e = tid; e < 528; e += 256) {
            const int pl = e / 66;
            const int rem = e - pl * 66;
            const int sel = rem / 33;
            const int u = rem - sel * 33;
            const ushort* src = (sel == 0 ? xhi : xlo)
                + ((size_t)(b * 256 + (ic0 >> 1) + pl)) * ((size_t)Lin * 2)
                + (size_t)t0 * 4 + (size_t)u * 8;
            short8v val;
            if (u * 8 + 7 < lim) {
                const uint2 lo2 = *(const uint2*)(src);
                const uint2 hi2 = *(const uint2*)(src + 4);
                union { uint2 a[2]; short8v s; } cv;
                cv.a[0] = lo2; cv.a[1] = hi2;
                val = cv.s;
            } else {
#pragma unroll
                for (int k = 0; k < 8; ++k)
                    val[k] = (u * 8 + k < lim) ? (short)src[k] : (short)0;
            }
            if (sel == 0) *(short8v*)&LXhi[pl][u * 4][0] = val;
            else          *(short8v*)&LXlo[pl][u * 4][0] = val;
        }
        __syncthreads();
        // --- compute: 2 K-steps of 32
#pragma unroll
        for (int k32l = 0; k32l < 2; ++k32l) {
            short8v ahi[2], alo[2], bhi[2], blo[2];
#pragma unroll
            for (int i = 0; i < 2; ++i) {
                const int ocl = (mt2 * 2 + i) * 16 + m;
                ahi[i] = *(const short8v*)&LWhi[k32l][ocl][quad * 8];
                alo[i] = *(const short8v*)&LWlo[k32l][ocl][quad * 8];
            }
#pragma unroll
            for (int j = 0; j < 2; ++j) {
                const int tl = (nt2 * 2 + j) * 16 + m;
                const int pl = k32l * 4 + quad;
                const short4v h0a = *(const short4v*)&LXhi[pl][tl * 2][0];
                const short4v h0b = *(const short4v*)&LXhi[pl][tl * 2 + 2][0];
                const short4v l0a = *(const short4v*)&LXlo[pl][tl * 2][0];
                const short4v l0b = *(const short4v*)&LXlo[pl][tl * 2 + 2][0];
                bhi[j] = __builtin_shufflevector(h0a, h0b, 0, 1, 2, 3, 4, 5, 6, 7);
                blo[j] = __builtin_shufflevector(l0a, l0b, 0, 1, 2, 3, 4, 5, 6, 7);
            }
#pragma unroll
            for (int i = 0; i < 2; ++i)
#pragma unroll
                for (int j = 0; j < 2; ++j) {
                    acc[i][j] = __builtin_amdgcn_mfma_f32_16x16x32_bf16(ahi[i], bhi[j], acc[i][j], 0, 0, 0);
                    acc[i][j] = __builtin_amdgcn_mfma_f32_16x16x32_bf16(ahi[i], blo[j], acc[i][j], 0, 0, 0);
                    acc[i][j] = __builtin_amdgcn_mfma_f32_16x16x32_bf16(alo[i], bhi[j], acc[i][j], 0, 0, 0);
                }
        }
    }

    // --- epilogue
    float lsum = 0.f, lsq = 0.f;
    uint* ohiU = (uint*)ohi;
    uint* oloU = (uint*)olo;
#pragma unroll
    for (int i = 0; i < 2; ++i) {
        const int ocb2 = ocb + (mt2 * 2 + i) * 16 + quad * 4;
#pragma unroll
        for (int j = 0; j < 2; ++j) {
            const int t = t0 + (nt2 * 2 + j) * 16 + m;
            if (t < Lout) {
                if (PAIRED) {
#pragma unroll
                    for (int pr = 0; pr < 2; ++pr) {
                        const float v0 = acc[i][j][pr * 2], v1 = acc[i][j][pr * 2 + 1];
                        const ushort h0 = f2bf(v0), h1 = f2bf(v1);
                        const ushort q0 = f2bf(v0 - b2f(h0)), q1 = f2bf(v1 - b2f(h1));
                        const uint p = (uint)((ocb2 >> 1) + pr);
                        const size_t uidx = ((size_t)(b * 256 + p)) * Lout + t;
                        ohiU[uidx] = (uint)h0 | ((uint)h1 << 16);
                        oloU[uidx] = (uint)q0 | ((uint)q1 << 16);
                        lsum += v0 + v1; lsq += v0 * v0 + v1 * v1;
                    }
                } else {
#pragma unroll
                    for (int r = 0; r < 4; ++r) {
                        const float v = acc[i][j][r];
                        oplain[((size_t)(b * 512 + ocb2 + r)) * Lout + t] = v;
                        lsum += v; lsq += v * v;
                    }
                }
            }
        }
    }
    __syncthreads();
    red[0][tid] = lsum; red[1][tid] = lsq;
    __syncthreads();
    for (int s2 = 128; s2 > 0; s2 >>= 1) {
        if (tid < s2) { red[0][tid] += red[0][tid + s2]; red[1][tid] += red[1][tid + s2]; }
        __syncthreads();
    }
    if (tid == 0) {
        atomicAdd(&stats[2 * b], red[0][0]);
        atomicAdd(&stats[2 * b + 1], red[1][0]);
    }
}

// ---------------------------------------------------------------------------
// norm_pair: GN(1grp)+affine+ReLU in place on pair-interleaved bf16 hi/lo.
// row = b*256 + pair; one uint = both channels of the pair at time t.
// ---------------------------------------------------------------------------
__global__ __launch_bounds__(256) void norm_pair(
    ushort* __restrict__ hhi, ushort* __restrict__ hlo,
    const float* __restrict__ stats,
    const float* __restrict__ gamma, const float* __restrict__ beta,
    int L, float invN)
{
    const int row = blockIdx.y;
    const int b = row >> 8, p = row & 255;
    const int t = blockIdx.x * 256 + threadIdx.x;
    if (t >= L) return;
    const int c0 = 2 * p, c1 = 2 * p + 1;
    const float mu = stats[2 * b] * invN;
    const float var = stats[2 * b + 1] * invN - mu * mu;
    const float rs = rsqrtf(var + 1e-5f);
    const float sc0 = rs * gamma[c0], sh0 = beta[c0] - mu * sc0;
    const float sc1 = rs * gamma[c1], sh1 = beta[c1] - mu * sc1;
    uint* hiU = (uint*)hhi;
    uint* loU = (uint*)hlo;
    const size_t idx = (size_t)row * L + t;
    const uint uh = hiU[idx], ul = loU[idx];
    const float v0 = b2f((ushort)(uh & 0xffff)) + b2f((ushort)(ul & 0xffff));
    const float v1 = b2f((ushort)(uh >> 16)) + b2f((ushort)(ul >> 16));
    const float n0 = fmaxf(v0 * sc0 + sh0, 0.f);
    const float n1 = fmaxf(v1 * sc1 + sh1, 0.f);
    const ushort h0 = f2bf(n0), h1 = f2bf(n1);
    const ushort q0 = f2bf(n0 - b2f(h0)), q1 = f2bf(n1 - b2f(h1));
    hiU[idx] = (uint)h0 | ((uint)h1 << 16);
    loU[idx] = (uint)q0 | ((uint)q1 << 16);
}

// ---------------------------------------------------------------------------
// norm_feat: GN+affine+ReLU on plain fp32 features, in place.
// ---------------------------------------------------------------------------
__global__ __launch_bounds__(256) void norm_feat(
    float* __restrict__ h, const float* __restrict__ stats,
    const float* __restrict__ gamma, const float* __restrict__ beta,
    int L, float invN)
{
    const int row = blockIdx.y;
    const int b = row >> 9, oc = row & 511;
    const int t = blockIdx.x * 256 + threadIdx.x;
    if (t >= L) return;
    const float mu = stats[2 * b] * invN;
    const float var = stats[2 * b + 1] * invN - mu * mu;
    const float rs = rsqrtf(var + 1e-5f);
    const float sc = rs * gamma[oc];
    const float sh = beta[oc] - mu * sc;
    const size_t i = (size_t)row * L + t;
    const float v = h[i] * sc + sh;
    h[i] = v > 0.f ? v : 0.f;
}

// ---------------------------------------------------------------------------
// aa_kernel: row squared-norms of features.
// ---------------------------------------------------------------------------
__global__ __launch_bounds__(256) void aa_kernel(
    const float* __restrict__ fX, const float* __restrict__ fY,
    float* __restrict__ aaX, float* __restrict__ aaY)
{
    const int wave = threadIdx.x >> 6, lane = threadIdx.x & 63;
    const int R = blockIdx.x * 4 + wave;
    const float* f = (R < 8192) ? fX : fY;
    const int r = R & 8191;
    const float* row = f + (size_t)r * 198;
    float s = 0.f;
#pragma unroll
    for (int k = 0; k < 4; ++k) {
        const int j = lane + 64 * k;
        if (j < 198) { const float v = row[j]; s += v * v; }
    }
#pragma unroll
    for (int off = 32; off > 0; off >>= 1) s += __shfl_xor(s, off);
    if (lane == 0) ((R < 8192) ? aaX : aaY)[r] = s;
}

// ---------------------------------------------------------------------------
// cost_kernel: C[b,n,m] = 0.5*max(aa[n]+bb[m]-2<p_n,q_m>, 0), D=198.
// ---------------------------------------------------------------------------
__global__ __launch_bounds__(256) void cost_kernel(
    const float* __restrict__ fX, const float* __restrict__ fY,
    const float* __restrict__ aaX, const float* __restrict__ aaY,
    float* __restrict__ Cxy, float* __restrict__ Cxx, float* __restrict__ Cyy,
    float* __restrict__ CTxy)
{
    const int z = blockIdx.z;
    const int mat = z >> 4, b = z & 15;
    const float *P, *Q, *aP, *aQ;
    float *Cm, *CT = nullptr;
    if (mat == 0) { P = fX; Q = fY; aP = aaX; aQ = aaY; Cm = Cxy; CT = CTxy; }
    else if (mat == 1) { P = fX; Q = fX; aP = aaX; aQ = aaX; Cm = Cxx; }
    else { P = fY; Q = fY; aP = aaY; aQ = aaY; Cm = Cyy; }

    const int n0 = blockIdx.x * 32, m0 = blockIdx.y * 32;
    __shared__ float LP[32][201], LQ[32][201];
    const int tid = threadIdx.x;
    for (int e = tid; e < 32 * 198; e += 256) {
        const int r = e / 198, d = e % 198;
        LP[r][d] = P[((size_t)b * 512 + n0 + r) * 198 + d];
        LQ[r][d] = Q[((size_t)b * 512 + m0 + r) * 198 + d];
    }
    __syncthreads();

    const int tx = tid & 31, ty = tid >> 5;
    float dot[4] = {0.f, 0.f, 0.f, 0.f};
    for (int d = 0; d < 198; ++d) {
        const float qv = LQ[tx][d];
#pragma unroll
        for (int q = 0; q < 4; ++q) dot[q] += LP[ty + 8 * q][d] * qv;
    }
    const int mm = m0 + tx;
    const float bbm = aQ[b * 512 + mm];
#pragma unroll
    for (int q = 0; q < 4; ++q) {
        const int n = n0 + ty + 8 * q;
        const float c = 0.5f * fmaxf(aP[b * 512 + n] + bbm - 2.f * dot[q], 0.f);
        Cm[((size_t)b * 512 + n) * 512 + mm] = c;
        if (CT) CT[((size_t)b * 512 + mm) * 512 + n] = c;
    }
}

// ---------------------------------------------------------------------------
// sink_update: dst[i] = eps*log512 - eps*LSE_j((src[j]-M[i,j])/eps)
// ---------------------------------------------------------------------------
__global__ __launch_bounds__(256) void sink_update(
    float* __restrict__ dst, const float* __restrict__ src,
    const float* __restrict__ M0, const float* __restrict__ M1,
    const float* __restrict__ M2)
{
    const int p = blockIdx.y;
    const int mat = p >> 4, b = p & 15;
    const float* M = (mat == 0) ? M0 : ((mat == 1) ? M1 : M2);
    const float* sp = src + (size_t)p * 512;
    __shared__ float sf[512];
    const int tid = threadIdx.x;
    sf[tid] = sp[tid] * INV_EPS_SINK;
    sf[tid + 256] = sp[tid + 256] * INV_EPS_SINK;
    __syncthreads();

    const int wave = tid >> 6, lane = tid & 63;
    const int i = blockIdx.x * 4 + wave;
    const float* row = M + ((size_t)b * 512 + i) * 512;

    float mx = -3.4e38f, ss = 0.f;
#pragma unroll
    for (int k = 0; k < 8; ++k) {
        const int j = lane + k * 64;
        const float arg = sf[j] - row[j] * INV_EPS_SINK;
        const float nm = fmaxf(mx, arg);
        ss = ss * __expf(mx - nm) + __expf(arg - nm);
        mx = nm;
    }
#pragma unroll
    for (int off = 32; off > 0; off >>= 1) {
        const float om = __shfl_xor(mx, off);
        const float os = __shfl_xor(ss, off);
        const float nm = fmaxf(mx, om);
        ss = ss * __expf(mx - nm) + os * __expf(om - nm);
        mx = nm;
    }
    if (lane == 0)
        dst[(size_t)p * 512 + i] = EPS_LOG512 - EPS_SINK * (mx + logf(ss));
}

// ---------------------------------------------------------------------------
__global__ __launch_bounds__(256) void final_kernel(
    const float* __restrict__ f, const float* __restrict__ g,
    float* __restrict__ out)
{
    const int b = blockIdx.x, tid = threadIdx.x;
    __shared__ float red[256];
    float a = 0.f;
    for (int n = tid; n < 512; n += 256) {
        const float xy = f[(0 * 16 + b) * 512 + n] + g[(0 * 16 + b) * 512 + n];
        const float xx = f[(1 * 16 + b) * 512 + n] + g[(1 * 16 + b) * 512 + n];
        const float yy = f[(2 * 16 + b) * 512 + n] + g[(2 * 16 + b) * 512 + n];
        a += xy - 0.5f * (xx + yy);
    }
    red[tid] = a;
    __syncthreads();
    for (int s2 = 128; s2 > 0; s2 >>= 1) {
        if (tid < s2) red[tid] += red[tid + s2];
        __syncthreads();
    }
    if (tid == 0) out[b] = red[0] * (1.0f / 512.0f);
}

// ---------------------------------------------------------------------------
extern "C" void kernel_launch(void* const* d_in, const int* in_sizes, int n_in,
                              void* d_out, int out_size, void* d_ws, size_t ws_size,
                              hipStream_t stream)
{
    (void)in_sizes; (void)n_in; (void)out_size; (void)ws_size;
    char* ws = (char*)d_ws;
    const float* yhat = (const float*)d_in[0];
    const float* ysig = (const float*)d_in[1];
    const float* Wl[5]; const float* gl[5]; const float* bl[5];
    for (int i = 0; i < 5; ++i) {
        Wl[i] = (const float*)d_in[2 + 3 * i];
        gl[i] = (const float*)d_in[3 + 3 * i];
        bl[i] = (const float*)d_in[4 + 3 * i];
    }
    float* out = (float*)d_out;
    float* statsA = (float*)(ws + O_STATS);

    hipMemsetAsync(statsA, 0, 512 * sizeof(float), stream);

    for (int s = 0; s < 2; ++s) {
        const float* wav = (s == 0) ? yhat : ysig;
        float* st = statsA + (size_t)s * 160;
        ushort* h1hi = (ushort*)(ws + O_H1HI); ushort* h1lo = (ushort*)(ws + O_H1LO);
        ushort* h2hi = (ushort*)(ws + O_H2HI); ushort* h2lo = (ushort*)(ws + O_H2LO);
        ushort* h3hi = (ushort*)(ws + O_H3HI); ushort* h3lo = (ushort*)(ws + O_H3LO);
        float* ft = (float*)(ws + ((s == 0) ? O_FEATX : O_FEATY));

        conv0_stats<<<dim3(25, 16), 256, 0, stream>>>(wav, Wl[0], st);

        conv1_mfma<<<dim3(25, 8, 16), 256, 0, stream>>>(
            wav, Wl[0], gl[0], bl[0], st, Wl[1], h1hi, h1lo, st + 32);
        norm_pair<<<dim3(7, 4096), 256, 0, stream>>>(
            h1hi, h1lo, st + 32, gl[1], bl[1], 1598, 1.f / (512.f * 1598.f));

        conv_mfma<true><<<dim3(13, 8, 16), 256, 0, stream>>>(
            h1hi, h1lo, Wl[2], h2hi, h2lo, nullptr, st + 64, 1598, 798);
        norm_pair<<<dim3(4, 4096), 256, 0, stream>>>(
            h2hi, h2lo, st + 64, gl[2], bl[2], 798, 1.f / (512.f * 798.f));

        conv_mfma<true><<<dim3(7, 8, 16), 256, 0, stream>>>(
            h2hi, h2lo, Wl[3], h3hi, h3lo, nullptr, st + 96, 798, 398);
        norm_pair<<<dim3(2, 4096), 256, 0, stream>>>(
            h3hi, h3lo, st + 96, gl[3], bl[3], 398, 1.f / (512.f * 398.f));

        conv_mfma<false><<<dim3(4, 8, 16), 256, 0, stream>>>(
            h3hi, h3lo, Wl[4], nullptr, nullptr, ft, st + 128, 398, 198);
        norm_feat<<<dim3(1, 8192), 256, 0, stream>>>(
            ft, st + 128, gl[4], bl[4], 198, 1.f / (512.f * 198.f));
    }

    float* featX = (float*)(ws + O_FEATX);
    float* featY = (float*)(ws + O_FEATY);
    aa_kernel<<<4096, 256, 0, stream>>>(featX, featY, (float*)(ws + O_AAX), (float*)(ws + O_AAY));
    cost_kernel<<<dim3(16, 16, 48), 256, 0, stream>>>(
        featX, featY, (float*)(ws + O_AAX), (float*)(ws + O_AAY),
        (float*)(ws + O_CXY), (float*)(ws + O_CXX), (float*)(ws + O_CYY),
        (float*)(ws + O_CTXY));

    hipMemsetAsync(ws + O_F, 0, 2 * 24576 * sizeof(float), stream);

    for (int it = 0; it < 50; ++it) {
        sink_update<<<dim3(128, 48), 256, 0, stream>>>(
            (float*)(ws + O_G), (float*)(ws + O_F),
            (float*)(ws + O_CTXY), (float*)(ws + O_CXX), (float*)(ws + O_CYY));
        sink_update<<<dim3(128, 48), 256, 0, stream>>>(
            (float*)(ws + O_F), (float*)(ws + O_G),
            (float*)(ws + O_CXY), (float*)(ws + O_CXX), (float*)(ws + O_CYY));
    }

    final_kernel<<<16, 256, 0, stream>>>((float*)(ws + O_F), (float*)(ws + O_G), out);
}

// Round 4
// 2837.644 us; speedup vs baseline: 3.3297x; 1.5633x over previous
//
#include <hip/hip_runtime.h>

typedef unsigned int uint;
typedef unsigned short ushort;
using half8v  = __attribute__((ext_vector_type(8))) _Float16;
using half4v  = __attribute__((ext_vector_type(4))) _Float16;
using float4v = __attribute__((ext_vector_type(4))) float;

#define EPS_SINK 0.0025f
#define INV_EPS_SINK 400.0f
#define EPS_LOG512 0.015595811562598769f

// ---- workspace layout (BYTE offsets), peak ~165 MB ----
static const size_t O_W1HI = 0ull;             // 512*512*8 f16 = 4,194,304 B
static const size_t O_W1LO = 4194304ull;
static const size_t O_W2HI = 8388608ull;       // 512*256*8 f16 = 2,097,152 B
static const size_t O_W2LO = 10485760ull;
static const size_t O_W3HI = 12582912ull;
static const size_t O_W3LO = 14680064ull;
static const size_t O_W4HI = 16777216ull;
static const size_t O_W4LO = 18874368ull;
static const size_t O_H0   = 20971520ull;      // 16*512*6400 f16 = 104,857,600 B
static const size_t O_H1   = 125829120ull;     // 16*256*1598 uint = 26,181,632 B
static const size_t O_H2   = 20971520ull;      // alias h0 (dead): 13,074,432 B
static const size_t O_H3   = 34045952ull;      // 6,520,832 B
static const size_t O_FEATX= 152010752ull;     // 16*512*198 fp32 = 6,488,064 B
static const size_t O_FEATY= 158498816ull;
static const size_t O_STATS= 164986880ull;     // 512 floats
// cost phase (convs dead):
static const size_t O_CXY  = 0ull;
static const size_t O_CTXY = 16777216ull;
static const size_t O_CXX  = 33554432ull;
static const size_t O_CYY  = 50331648ull;
static const size_t O_AAX  = 67108864ull;
static const size_t O_AAY  = 67141632ull;
static const size_t O_F    = 67174400ull;
static const size_t O_G    = 67272704ull;

// ---------------------------------------------------------------------------
// prep_w: split conv weights fp32 -> f16 hi/lo. W1 kept [oc][ic][8 taps];
// W2-4 stored pair-interleaved [oc][icpair][dt0 icA, dt0 icB, dt1 icA, ...].
// ---------------------------------------------------------------------------
__global__ __launch_bounds__(256) void prep_w(
    const float* __restrict__ W1, const float* __restrict__ W2,
    const float* __restrict__ W3, const float* __restrict__ W4,
    _Float16* __restrict__ w1hi, _Float16* __restrict__ w1lo,
    _Float16* __restrict__ w2hi, _Float16* __restrict__ w2lo,
    _Float16* __restrict__ w3hi, _Float16* __restrict__ w3lo,
    _Float16* __restrict__ w4hi, _Float16* __restrict__ w4lo)
{
    const int layer = blockIdx.y;
    const int e = blockIdx.x * 256 + threadIdx.x;
    float v[8];
    _Float16 *dh, *dl;
    if (layer == 0) {
        const float4 a = *(const float4*)(W1 + (size_t)e * 8);
        const float4 c = *(const float4*)(W1 + (size_t)e * 8 + 4);
        v[0]=a.x; v[1]=a.y; v[2]=a.z; v[3]=a.w; v[4]=c.x; v[5]=c.y; v[6]=c.z; v[7]=c.w;
        dh = w1hi; dl = w1lo;
    } else {
        if (e >= 131072) return;
        const float* W = (layer == 1) ? W2 : (layer == 2) ? W3 : W4;
        dh = (layer == 1) ? w2hi : (layer == 2) ? w3hi : w4hi;
        dl = (layer == 1) ? w2lo : (layer == 2) ? w3lo : w4lo;
        const int oc = e >> 8, icp = e & 255;
        const float4 a = *(const float4*)(W + ((size_t)oc * 512 + icp * 2) * 4);
        const float4 c = *(const float4*)(W + ((size_t)oc * 512 + icp * 2 + 1) * 4);
        v[0]=a.x; v[1]=c.x; v[2]=a.y; v[3]=c.y; v[4]=a.z; v[5]=c.z; v[6]=a.w; v[7]=c.w;
    }
    half8v hi, lo;
#pragma unroll
    for (int k = 0; k < 8; ++k) {
        const _Float16 h = (_Float16)v[k];
        hi[k] = h;
        lo[k] = (_Float16)(v[k] - (float)h);
    }
    *(half8v*)(dh + (size_t)e * 8) = hi;
    *(half8v*)(dl + (size_t)e * 8) = lo;
}

// ---------------------------------------------------------------------------
// conv0_store: raw conv0 (k=10,s=5) -> h0 f16 [b][512][6400] + GN stats.
// ---------------------------------------------------------------------------
__global__ __launch_bounds__(256) void conv0_store(
    const float* __restrict__ wav, const float* __restrict__ W0,
    _Float16* __restrict__ h0, float* __restrict__ stats)
{
    __shared__ float LW[5120];
    __shared__ float red[2][256];
    const int tid = threadIdx.x;
    for (int e = tid; e < 5120; e += 256) LW[e] = W0[e];

    const int b = blockIdx.y;
    const int t = blockIdx.x * 256 + tid;
    const bool valid = (t < 6399);
    float xv[10];
#pragma unroll
    for (int d = 0; d < 10; ++d) xv[d] = 0.f;
    if (valid) {
        const float* wp = wav + (size_t)b * 32000 + (size_t)t * 5;
#pragma unroll
        for (int d = 0; d < 10; ++d) xv[d] = wp[d];
    }
    __syncthreads();

    float lsum = 0.f, lsq = 0.f;
    _Float16* hb = h0 + (size_t)b * 512 * 6400;
    for (int oc = 0; oc < 512; ++oc) {
        float a = 0.f;
#pragma unroll
        for (int d = 0; d < 10; ++d) a += LW[oc * 10 + d] * xv[d];
        if (valid) {
            hb[(size_t)oc * 6400 + t] = (_Float16)a;
            lsum += a; lsq += a * a;
        }
    }
    red[0][tid] = lsum; red[1][tid] = lsq;
    __syncthreads();
    for (int s2 = 128; s2 > 0; s2 >>= 1) {
        if (tid < s2) { red[0][tid] += red[0][tid + s2]; red[1][tid] += red[1][tid + s2]; }
        __syncthreads();
    }
    if (tid == 0) {
        atomicAdd(&stats[2 * b], red[0][0]);
        atomicAdd(&stats[2 * b + 1], red[1][0]);
    }
}

// ---------------------------------------------------------------------------
// conv1_mfma: layer1 (K=8,S=4) from raw-f16 h0; applies GN0+ReLU inline in
// staging. MFMA f16, W compensated hi/lo (2 products). Output single f16
// pair-interleaved [b][256 pairs][1598][2] + GN1 stats.
// ---------------------------------------------------------------------------
__global__ __launch_bounds__(256) void conv1_mfma(
    const _Float16* __restrict__ h0, const float* __restrict__ stats0,
    const float* __restrict__ g0, const float* __restrict__ b0,
    const _Float16* __restrict__ w1hi, const _Float16* __restrict__ w1lo,
    _Float16* __restrict__ oh, float* __restrict__ stats1)
{
    __shared__ _Float16 LWhi[2][64][40], LWlo[2][64][40];  // [k32l][oc][32+pad]
    __shared__ _Float16 LX[8][272];                        // [ic][sample]
    __shared__ float red[2][256];

    const int tid  = threadIdx.x;
    const int lane = tid & 63, wv = tid >> 6;
    const int m    = lane & 15, quad = lane >> 4;
    const int mt2  = wv >> 1, nt2 = wv & 1;
    const int b    = blockIdx.z;
    const int ocb  = blockIdx.y * 64;
    const int t0   = blockIdx.x * 64;
    const int Lout = 1598;

    const float invN0 = 1.f / (512.f * 6399.f);
    const float mu = stats0[2 * b] * invN0;
    const float var = stats0[2 * b + 1] * invN0 - mu * mu;
    const float rs = rsqrtf(var + 1e-5f);

    float4v acc[2][2];
#pragma unroll
    for (int i = 0; i < 2; ++i)
#pragma unroll
        for (int j = 0; j < 2; ++j) acc[i][j] = (float4v){0.f, 0.f, 0.f, 0.f};

    const _Float16* hb = h0 + (size_t)b * 512 * 6400;
    const int gbase = t0 * 4;

    for (int ic0 = 0; ic0 < 512; ic0 += 8) {
        __syncthreads();
        // --- stage W (pure copy from prepped hi/lo)
#pragma unroll
        for (int r = 0; r < 2; ++r) {
            const int e = tid + r * 256;
            const int k32l = e >> 8, oc = (e >> 2) & 63, q = e & 3;
            const size_t so = ((size_t)(ocb + oc) * 512 + ic0 + k32l * 4 + q) * 8;
            *(half8v*)&LWhi[k32l][oc][q * 8] = *(const half8v*)(w1hi + so);
            *(half8v*)&LWlo[k32l][oc][q * 8] = *(const half8v*)(w1lo + so);
        }
        // --- stage X: copy + affine + relu (272 16B-units)
        for (int e = tid; e < 272; e += 256) {
            const int ic = e / 34, u = e - ic * 34;
            const int gj = gbase + u * 8;
            const float sc = rs * g0[ic0 + ic];
            const float sh = b0[ic0 + ic] - mu * sc;
            const _Float16* src = hb + (size_t)(ic0 + ic) * 6400 + gj;
            half8v raw;
            if (gj + 7 < 6399) raw = *(const half8v*)src;
            else {
#pragma unroll
                for (int k = 0; k < 8; ++k) raw[k] = (gj + k < 6399) ? src[k] : (_Float16)0.f;
            }
            half8v nv;
#pragma unroll
            for (int k = 0; k < 8; ++k)
                nv[k] = (_Float16)fmaxf((float)raw[k] * sc + sh, 0.f);
            *(half8v*)&LX[ic][u * 8] = nv;
        }
        __syncthreads();
        // --- compute: 2 K-steps of 32
#pragma unroll
        for (int k32l = 0; k32l < 2; ++k32l) {
            half8v ahi[2], alo[2], bf[2];
#pragma unroll
            for (int i = 0; i < 2; ++i) {
                const int ocl = (mt2 * 2 + i) * 16 + m;
                ahi[i] = *(const half8v*)&LWhi[k32l][ocl][quad * 8];
                alo[i] = *(const half8v*)&LWlo[k32l][ocl][quad * 8];
            }
#pragma unroll
            for (int j = 0; j < 2; ++j) {
                const int tl = (nt2 * 2 + j) * 16 + m;
                const int icl = k32l * 4 + quad;
                const half4v x0 = *(const half4v*)&LX[icl][tl * 4];
                const half4v x1 = *(const half4v*)&LX[icl][tl * 4 + 4];
                bf[j] = __builtin_shufflevector(x0, x1, 0, 1, 2, 3, 4, 5, 6, 7);
            }
#pragma unroll
            for (int i = 0; i < 2; ++i)
#pragma unroll
                for (int j = 0; j < 2; ++j) {
                    acc[i][j] = __builtin_amdgcn_mfma_f32_16x16x32_f16(ahi[i], bf[j], acc[i][j], 0, 0, 0);
                    acc[i][j] = __builtin_amdgcn_mfma_f32_16x16x32_f16(alo[i], bf[j], acc[i][j], 0, 0, 0);
                }
        }
    }

    // --- epilogue: pack f16 pairs + stats
    float lsum = 0.f, lsq = 0.f;
    uint* ohU = (uint*)oh;
#pragma unroll
    for (int i = 0; i < 2; ++i) {
        const int ocb2 = ocb + (mt2 * 2 + i) * 16 + quad * 4;
#pragma unroll
        for (int j = 0; j < 2; ++j) {
            const int t = t0 + (nt2 * 2 + j) * 16 + m;
            if (t < Lout) {
#pragma unroll
                for (int pr = 0; pr < 2; ++pr) {
                    const float v0 = acc[i][j][pr * 2], v1 = acc[i][j][pr * 2 + 1];
                    union { uint u; _Float16 h[2]; } pk;
                    pk.h[0] = (_Float16)v0; pk.h[1] = (_Float16)v1;
                    const uint p = (uint)((ocb2 >> 1) + pr);
                    ohU[((size_t)(b * 256 + p)) * Lout + t] = pk.u;
                    lsum += v0 + v1; lsq += v0 * v0 + v1 * v1;
                }
            }
        }
    }
    __syncthreads();
    red[0][tid] = lsum; red[1][tid] = lsq;
    __syncthreads();
    for (int s2 = 128; s2 > 0; s2 >>= 1) {
        if (tid < s2) { red[0][tid] += red[0][tid + s2]; red[1][tid] += red[1][tid + s2]; }
        __syncthreads();
    }
    if (tid == 0) {
        atomicAdd(&stats1[2 * b], red[0][0]);
        atomicAdd(&stats1[2 * b + 1], red[1][0]);
    }
}

// ---------------------------------------------------------------------------
// conv_mfma: layers 2-4 (K=4,S=2). Input single f16 pair-interleaved.
// W prepped hi/lo (2 MFMAs). PAIRED: f16 pair-interleaved out; else fp32.
// ---------------------------------------------------------------------------
template <bool PAIRED>
__global__ __launch_bounds__(256) void conv_mfma(
    const _Float16* __restrict__ x,
    const _Float16* __restrict__ whi, const _Float16* __restrict__ wlo,
    _Float16* __restrict__ oh, float* __restrict__ oplain,
    float* __restrict__ stats, int Lin, int Lout)
{
    __shared__ _Float16 LWhi[2][64][40], LWlo[2][64][40];
    __shared__ _Float16 LX[8][272];                       // [icpair][sample*2+member]
    __shared__ float red[2][256];

    const int tid  = threadIdx.x;
    const int lane = tid & 63, wv = tid >> 6;
    const int m    = lane & 15, quad = lane >> 4;
    const int mt2  = wv >> 1, nt2 = wv & 1;
    const int b    = blockIdx.z;
    const int ocb  = blockIdx.y * 64;
    const int t0   = blockIdx.x * 64;

    float4v acc[2][2];
#pragma unroll
    for (int i = 0; i < 2; ++i)
#pragma unroll
        for (int j = 0; j < 2; ++j) acc[i][j] = (float4v){0.f, 0.f, 0.f, 0.f};

    const int lim = (Lin - t0 * 2) * 2;   // valid f16s from row offset t0*4

    for (int ic0 = 0; ic0 < 512; ic0 += 16) {
        __syncthreads();
        // --- stage W (copy)
#pragma unroll
        for (int r = 0; r < 2; ++r) {
            const int e = tid + r * 256;
            const int k32l = e >> 8, oc = (e >> 2) & 63, q = e & 3;
            const size_t so = ((size_t)(ocb + oc) * 256 + (ic0 >> 1) + k32l * 4 + q) * 8;
            *(half8v*)&LWhi[k32l][oc][q * 8] = *(const half8v*)(whi + so);
            *(half8v*)&LWlo[k32l][oc][q * 8] = *(const half8v*)(wlo + so);
        }
        // --- stage X (copy, 272 16B-units)
        for (int e = tid; e < 272; e += 256) {
            const int pl = e / 34, u = e - pl * 34;
            const _Float16* src = x + ((size_t)(b * 256 + (ic0 >> 1) + pl)) * ((size_t)Lin * 2)
                                   + (size_t)t0 * 4 + (size_t)u * 8;
            half8v val;
            if (u * 8 + 7 < lim) val = *(const half8v*)src;
            else {
#pragma unroll
                for (int k = 0; k < 8; ++k) val[k] = (u * 8 + k < lim) ? src[k] : (_Float16)0.f;
            }
            *(half8v*)&LX[pl][u * 8] = val;
        }
        __syncthreads();
        // --- compute
#pragma unroll
        for (int k32l = 0; k32l < 2; ++k32l) {
            half8v ahi[2], alo[2], bf[2];
#pragma unroll
            for (int i = 0; i < 2; ++i) {
                const int ocl = (mt2 * 2 + i) * 16 + m;
                ahi[i] = *(const half8v*)&LWhi[k32l][ocl][quad * 8];
                alo[i] = *(const half8v*)&LWlo[k32l][ocl][quad * 8];
            }
#pragma unroll
            for (int j = 0; j < 2; ++j) {
                const int tl = (nt2 * 2 + j) * 16 + m;
                const int pl = k32l * 4 + quad;
                const half4v x0 = *(const half4v*)&LX[pl][tl * 4];
                const half4v x1 = *(const half4v*)&LX[pl][tl * 4 + 4];
                bf[j] = __builtin_shufflevector(x0, x1, 0, 1, 2, 3, 4, 5, 6, 7);
            }
#pragma unroll
            for (int i = 0; i < 2; ++i)
#pragma unroll
                for (int j = 0; j < 2; ++j) {
                    acc[i][j] = __builtin_amdgcn_mfma_f32_16x16x32_f16(ahi[i], bf[j], acc[i][j], 0, 0, 0);
                    acc[i][j] = __builtin_amdgcn_mfma_f32_16x16x32_f16(alo[i], bf[j], acc[i][j], 0, 0, 0);
                }
        }
    }

    // --- epilogue
    float lsum = 0.f, lsq = 0.f;
    uint* ohU = (uint*)oh;
#pragma unroll
    for (int i = 0; i < 2; ++i) {
        const int ocb2 = ocb + (mt2 * 2 + i) * 16 + quad * 4;
#pragma unroll
        for (int j = 0; j < 2; ++j) {
            const int t = t0 + (nt2 * 2 + j) * 16 + m;
            if (t < Lout) {
                if (PAIRED) {
#pragma unroll
                    for (int pr = 0; pr < 2; ++pr) {
                        const float v0 = acc[i][j][pr * 2], v1 = acc[i][j][pr * 2 + 1];
                        union { uint u; _Float16 h[2]; } pk;
                        pk.h[0] = (_Float16)v0; pk.h[1] = (_Float16)v1;
                        const uint p = (uint)((ocb2 >> 1) + pr);
                        ohU[((size_t)(b * 256 + p)) * Lout + t] = pk.u;
                        lsum += v0 + v1; lsq += v0 * v0 + v1 * v1;
                    }
                } else {
#pragma unroll
                    for (int r = 0; r < 4; ++r) {
                        const float v = acc[i][j][r];
                        oplain[((size_t)(b * 512 + ocb2 + r)) * Lout + t] = v;
                        lsum += v; lsq += v * v;
                    }
                }
            }
        }
    }
    __syncthreads();
    red[0][tid] = lsum; red[1][tid] = lsq;
    __syncthreads();
    for (int s2 = 128; s2 > 0; s2 >>= 1) {
        if (tid < s2) { red[0][tid] += red[0][tid + s2]; red[1][tid] += red[1][tid + s2]; }
        __syncthreads();
    }
    if (tid == 0) {
        atomicAdd(&stats[2 * b], red[0][0]);
        atomicAdd(&stats[2 * b + 1], red[1][0]);
    }
}

// ---------------------------------------------------------------------------
// norm_pair: GN(1grp)+affine+ReLU in place on pair-interleaved f16.
// ---------------------------------------------------------------------------
__global__ __launch_bounds__(256) void norm_pair(
    uint* __restrict__ h, const float* __restrict__ stats,
    const float* __restrict__ gamma, const float* __restrict__ beta,
    int L, float invN)
{
    const int row = blockIdx.y;
    const int b = row >> 8, p = row & 255;
    const int t = blockIdx.x * 256 + threadIdx.x;
    if (t >= L) return;
    const int c0 = 2 * p, c1 = 2 * p + 1;
    const float mu = stats[2 * b] * invN;
    const float var = stats[2 * b + 1] * invN - mu * mu;
    const float rs = rsqrtf(var + 1e-5f);
    const float sc0 = rs * gamma[c0], sh0 = beta[c0] - mu * sc0;
    const float sc1 = rs * gamma[c1], sh1 = beta[c1] - mu * sc1;
    const size_t idx = (size_t)row * L + t;
    union { uint u; _Float16 h2[2]; } pk;
    pk.u = h[idx];
    const float n0 = fmaxf((float)pk.h2[0] * sc0 + sh0, 0.f);
    const float n1 = fmaxf((float)pk.h2[1] * sc1 + sh1, 0.f);
    pk.h2[0] = (_Float16)n0; pk.h2[1] = (_Float16)n1;
    h[idx] = pk.u;
}

// ---------------------------------------------------------------------------
// norm_feat: GN+affine+ReLU on plain fp32 features, in place.
// ---------------------------------------------------------------------------
__global__ __launch_bounds__(256) void norm_feat(
    float* __restrict__ h, const float* __restrict__ stats,
    const float* __restrict__ gamma, const float* __restrict__ beta,
    int L, float invN)
{
    const int row = blockIdx.y;
    const int b = row >> 9, oc = row & 511;
    const int t = blockIdx.x * 256 + threadIdx.x;
    if (t >= L) return;
    const float mu = stats[2 * b] * invN;
    const float var = stats[2 * b + 1] * invN - mu * mu;
    const float rs = rsqrtf(var + 1e-5f);
    const float sc = rs * gamma[oc];
    const float sh = beta[oc] - mu * sc;
    const size_t i = (size_t)row * L + t;
    const float v = h[i] * sc + sh;
    h[i] = v > 0.f ? v : 0.f;
}

// ---------------------------------------------------------------------------
// aa_kernel: row squared-norms of features.
// ---------------------------------------------------------------------------
__global__ __launch_bounds__(256) void aa_kernel(
    const float* __restrict__ fX, const float* __restrict__ fY,
    float* __restrict__ aaX, float* __restrict__ aaY)
{
    const int wave = threadIdx.x >> 6, lane = threadIdx.x & 63;
    const int R = blockIdx.x * 4 + wave;
    const float* f = (R < 8192) ? fX : fY;
    const int r = R & 8191;
    const float* row = f + (size_t)r * 198;
    float s = 0.f;
#pragma unroll
    for (int k = 0; k < 4; ++k) {
        const int j = lane + 64 * k;
        if (j < 198) { const float v = row[j]; s += v * v; }
    }
#pragma unroll
    for (int off = 32; off > 0; off >>= 1) s += __shfl_xor(s, off);
    if (lane == 0) ((R < 8192) ? aaX : aaY)[r] = s;
}

// ---------------------------------------------------------------------------
// cost_kernel: C[b,n,m] = 0.5*max(aa[n]+bb[m]-2<p_n,q_m>, 0), D=198.
// ---------------------------------------------------------------------------
__global__ __launch_bounds__(256) void cost_kernel(
    const float* __restrict__ fX, const float* __restrict__ fY,
    const float* __restrict__ aaX, const float* __restrict__ aaY,
    float* __restrict__ Cxy, float* __restrict__ Cxx, float* __restrict__ Cyy,
    float* __restrict__ CTxy)
{
    const int z = blockIdx.z;
    const int mat = z >> 4, b = z & 15;
    const float *P, *Q, *aP, *aQ;
    float *Cm, *CT = nullptr;
    if (mat == 0) { P = fX; Q = fY; aP = aaX; aQ = aaY; Cm = Cxy; CT = CTxy; }
    else if (mat == 1) { P = fX; Q = fX; aP = aaX; aQ = aaX; Cm = Cxx; }
    else { P = fY; Q = fY; aP = aaY; aQ = aaY; Cm = Cyy; }

    const int n0 = blockIdx.x * 32, m0 = blockIdx.y * 32;
    __shared__ float LP[32][201], LQ[32][201];
    const int tid = threadIdx.x;
    for (int e = tid; e < 32 * 198; e += 256) {
        const int r = e / 198, d = e % 198;
        LP[r][d] = P[((size_t)b * 512 + n0 + r) * 198 + d];
        LQ[r][d] = Q[((size_t)b * 512 + m0 + r) * 198 + d];
    }
    __syncthreads();

    const int tx = tid & 31, ty = tid >> 5;
    float dot[4] = {0.f, 0.f, 0.f, 0.f};
    for (int d = 0; d < 198; ++d) {
        const float qv = LQ[tx][d];
#pragma unroll
        for (int q = 0; q < 4; ++q) dot[q] += LP[ty + 8 * q][d] * qv;
    }
    const int mm = m0 + tx;
    const float bbm = aQ[b * 512 + mm];
#pragma unroll
    for (int q = 0; q < 4; ++q) {
        const int n = n0 + ty + 8 * q;
        const float c = 0.5f * fmaxf(aP[b * 512 + n] + bbm - 2.f * dot[q], 0.f);
        Cm[((size_t)b * 512 + n) * 512 + mm] = c;
        if (CT) CT[((size_t)b * 512 + mm) * 512 + n] = c;
    }
}

// ---------------------------------------------------------------------------
// sink_update: dst[i] = eps*log512 - eps*LSE_j((src[j]-M[i,j])/eps)
// ---------------------------------------------------------------------------
__global__ __launch_bounds__(256) void sink_update(
    float* __restrict__ dst, const float* __restrict__ src,
    const float* __restrict__ M0, const float* __restrict__ M1,
    const float* __restrict__ M2)
{
    const int p = blockIdx.y;
    const int mat = p >> 4, b = p & 15;
    const float* M = (mat == 0) ? M0 : ((mat == 1) ? M1 : M2);
    const float* sp = src + (size_t)p * 512;
    __shared__ float sf[512];
    const int tid = threadIdx.x;
    sf[tid] = sp[tid] * INV_EPS_SINK;
    sf[tid + 256] = sp[tid + 256] * INV_EPS_SINK;
    __syncthreads();

    const int wave = tid >> 6, lane = tid & 63;
    const int i = blockIdx.x * 4 + wave;
    const float* row = M + ((size_t)b * 512 + i) * 512;

    float mx = -3.4e38f, ss = 0.f;
#pragma unroll
    for (int k = 0; k < 8; ++k) {
        const int j = lane + k * 64;
        const float arg = sf[j] - row[j] * INV_EPS_SINK;
        const float nm = fmaxf(mx, arg);
        ss = ss * __expf(mx - nm) + __expf(arg - nm);
        mx = nm;
    }
#pragma unroll
    for (int off = 32; off > 0; off >>= 1) {
        const float om = __shfl_xor(mx, off);
        const float os = __shfl_xor(ss, off);
        const float nm = fmaxf(mx, om);
        ss = ss * __expf(mx - nm) + os * __expf(om - nm);
        mx = nm;
    }
    if (lane == 0)
        dst[(size_t)p * 512 + i] = EPS_LOG512 - EPS_SINK * (mx + logf(ss));
}

// ---------------------------------------------------------------------------
__global__ __launch_bounds__(256) void final_kernel(
    const float* __restrict__ f, const float* __restrict__ g,
    float* __restrict__ out)
{
    const int b = blockIdx.x, tid = threadIdx.x;
    __shared__ float red[256];
    float a = 0.f;
    for (int n = tid; n < 512; n += 256) {
        const float xy = f[(0 * 16 + b) * 512 + n] + g[(0 * 16 + b) * 512 + n];
        const float xx = f[(1 * 16 + b) * 512 + n] + g[(1 * 16 + b) * 512 + n];
        const float yy = f[(2 * 16 + b) * 512 + n] + g[(2 * 16 + b) * 512 + n];
        a += xy - 0.5f * (xx + yy);
    }
    red[tid] = a;
    __syncthreads();
    for (int s2 = 128; s2 > 0; s2 >>= 1) {
        if (tid < s2) red[tid] += red[tid + s2];
        __syncthreads();
    }
    if (tid == 0) out[b] = red[0] * (1.0f / 512.0f);
}

// ---------------------------------------------------------------------------
extern "C" void kernel_launch(void* const* d_in, const int* in_sizes, int n_in,
                              void* d_out, int out_size, void* d_ws, size_t ws_size,
                              hipStream_t stream)
{
    (void)in_sizes; (void)n_in; (void)out_size; (void)ws_size;
    char* ws = (char*)d_ws;
    const float* yhat = (const float*)d_in[0];
    const float* ysig = (const float*)d_in[1];
    const float* Wl[5]; const float* gl[5]; const float* bl[5];
    for (int i = 0; i < 5; ++i) {
        Wl[i] = (const float*)d_in[2 + 3 * i];
        gl[i] = (const float*)d_in[3 + 3 * i];
        bl[i] = (const float*)d_in[4 + 3 * i];
    }
    float* out = (float*)d_out;
    float* statsA = (float*)(ws + O_STATS);

    _Float16* w1hi = (_Float16*)(ws + O_W1HI); _Float16* w1lo = (_Float16*)(ws + O_W1LO);
    _Float16* w2hi = (_Float16*)(ws + O_W2HI); _Float16* w2lo = (_Float16*)(ws + O_W2LO);
    _Float16* w3hi = (_Float16*)(ws + O_W3HI); _Float16* w3lo = (_Float16*)(ws + O_W3LO);
    _Float16* w4hi = (_Float16*)(ws + O_W4HI); _Float16* w4lo = (_Float16*)(ws + O_W4LO);
    _Float16* h0 = (_Float16*)(ws + O_H0);
    _Float16* h1 = (_Float16*)(ws + O_H1);
    _Float16* h2 = (_Float16*)(ws + O_H2);
    _Float16* h3 = (_Float16*)(ws + O_H3);

    hipMemsetAsync(statsA, 0, 512 * sizeof(float), stream);
    prep_w<<<dim3(1024, 4), 256, 0, stream>>>(Wl[1], Wl[2], Wl[3], Wl[4],
        w1hi, w1lo, w2hi, w2lo, w3hi, w3lo, w4hi, w4lo);

    for (int s = 0; s < 2; ++s) {
        const float* wav = (s == 0) ? yhat : ysig;
        float* st = statsA + (size_t)s * 160;
        float* ft = (float*)(ws + ((s == 0) ? O_FEATX : O_FEATY));

        conv0_store<<<dim3(25, 16), 256, 0, stream>>>(wav, Wl[0], h0, st);

        conv1_mfma<<<dim3(25, 8, 16), 256, 0, stream>>>(
            h0, st, gl[0], bl[0], w1hi, w1lo, h1, st + 32);
        norm_pair<<<dim3(7, 4096), 256, 0, stream>>>(
            (uint*)h1, st + 32, gl[1], bl[1], 1598, 1.f / (512.f * 1598.f));

        conv_mfma<true><<<dim3(13, 8, 16), 256, 0, stream>>>(
            h1, w2hi, w2lo, h2, nullptr, st + 64, 1598, 798);
        norm_pair<<<dim3(4, 4096), 256, 0, stream>>>(
            (uint*)h2, st + 64, gl[2], bl[2], 798, 1.f / (512.f * 798.f));

        conv_mfma<true><<<dim3(7, 8, 16), 256, 0, stream>>>(
            h2, w3hi, w3lo, h3, nullptr, st + 96, 798, 398);
        norm_pair<<<dim3(2, 4096), 256, 0, stream>>>(
            (uint*)h3, st + 96, gl[3], bl[3], 398, 1.f / (512.f * 398.f));

        conv_mfma<false><<<dim3(4, 8, 16), 256, 0, stream>>>(
            h3, w4hi, w4lo, nullptr, ft, st + 128, 398, 198);
        norm_feat<<<dim3(1, 8192), 256, 0, stream>>>(
            ft, st + 128, gl[4], bl[4], 198, 1.f / (512.f * 198.f));
    }

    float* featX = (float*)(ws + O_FEATX);
    float* featY = (float*)(ws + O_FEATY);
    aa_kernel<<<4096, 256, 0, stream>>>(featX, featY, (float*)(ws + O_AAX), (float*)(ws + O_AAY));
    cost_kernel<<<dim3(16, 16, 48), 256, 0, stream>>>(
        featX, featY, (float*)(ws + O_AAX), (float*)(ws + O_AAY),
        (float*)(ws + O_CXY), (float*)(ws + O_CXX), (float*)(ws + O_CYY),
        (float*)(ws + O_CTXY));

    hipMemsetAsync(ws + O_F, 0, 2 * 24576 * sizeof(float), stream);

    for (int it = 0; it < 50; ++it) {
        sink_update<<<dim3(128, 48), 256, 0, stream>>>(
            (float*)(ws + O_G), (float*)(ws + O_F),
            (float*)(ws + O_CTXY), (float*)(ws + O_CXX), (float*)(ws + O_CYY));
        sink_update<<<dim3(128, 48), 256, 0, stream>>>(
            (float*)(ws + O_F), (float*)(ws + O_G),
            (float*)(ws + O_CXY), (float*)(ws + O_CXX), (float*)(ws + O_CYY));
    }

    final_kernel<<<16, 256, 0, stream>>>((float*)(ws + O_F), (float*)(ws + O_G), out);
}

// Round 7
// 2651.905 us; speedup vs baseline: 3.5629x; 1.0700x over previous
//
#include <hip/hip_runtime.h>

typedef unsigned int uint;
typedef unsigned short ushort;
using half8v  = __attribute__((ext_vector_type(8))) _Float16;
using half4v  = __attribute__((ext_vector_type(4))) _Float16;
using float4v = __attribute__((ext_vector_type(4))) float;

#define EPS_SINK 0.0025f
#define INV_EPS_SINK 400.0f
#define EPS_LOG512 0.015595811562598769f

// ---- workspace layout (BYTE offsets), peak ~165 MB ----
static const size_t O_W1HI = 0ull;             // 512*512*8 f16 = 4,194,304 B
static const size_t O_W1LO = 4194304ull;
static const size_t O_W2HI = 8388608ull;
static const size_t O_W2LO = 10485760ull;
static const size_t O_W3HI = 12582912ull;
static const size_t O_W3LO = 14680064ull;
static const size_t O_W4HI = 16777216ull;
static const size_t O_W4LO = 18874368ull;
static const size_t O_H0   = 20971520ull;      // 16*512*6400 f16 = 104,857,600 B
static const size_t O_H1   = 125829120ull;     // 16*256*1598 uint = 26,181,632 B
static const size_t O_H2   = 20971520ull;      // alias h0 (dead after conv1)
static const size_t O_H3   = 34045952ull;
static const size_t O_FEATX= 152010752ull;     // 16*512*198 fp32
static const size_t O_FEATY= 158498816ull;
static const size_t O_STATS= 164986880ull;     // 512 floats
// cost phase (weights/h0/h1 all dead).  C stored f16, value = 100*C:
static const size_t O_CXY  = 0ull;             // 8,388,608 B each
static const size_t O_CTXY = 8388608ull;
static const size_t O_CXX  = 16777216ull;
static const size_t O_CYY  = 25165824ull;
static const size_t O_AAX  = 33554432ull;      // 32,768 B each
static const size_t O_AAY  = 33587200ull;
static const size_t O_F    = 33619968ull;      // 3*16*512 fp32 = 98,304 B
static const size_t O_G    = 33718272ull;

// ---------------------------------------------------------------------------
// prep_w: split conv weights fp32 -> f16 hi/lo. W1 [oc][ic][8 taps];
// W2-4 pair-interleaved [oc][icpair][dt0 icA, dt0 icB, dt1 icA, ...].
// ---------------------------------------------------------------------------
__global__ __launch_bounds__(256) void prep_w(
    const float* __restrict__ W1, const float* __restrict__ W2,
    const float* __restrict__ W3, const float* __restrict__ W4,
    _Float16* __restrict__ w1hi, _Float16* __restrict__ w1lo,
    _Float16* __restrict__ w2hi, _Float16* __restrict__ w2lo,
    _Float16* __restrict__ w3hi, _Float16* __restrict__ w3lo,
    _Float16* __restrict__ w4hi, _Float16* __restrict__ w4lo)
{
    const int layer = blockIdx.y;
    const int e = blockIdx.x * 256 + threadIdx.x;
    float v[8];
    _Float16 *dh, *dl;
    if (layer == 0) {
        const float4 a = *(const float4*)(W1 + (size_t)e * 8);
        const float4 c = *(const float4*)(W1 + (size_t)e * 8 + 4);
        v[0]=a.x; v[1]=a.y; v[2]=a.z; v[3]=a.w; v[4]=c.x; v[5]=c.y; v[6]=c.z; v[7]=c.w;
        dh = w1hi; dl = w1lo;
    } else {
        if (e >= 131072) return;
        const float* W = (layer == 1) ? W2 : (layer == 2) ? W3 : W4;
        dh = (layer == 1) ? w2hi : (layer == 2) ? w3hi : w4hi;
        dl = (layer == 1) ? w2lo : (layer == 2) ? w3lo : w4lo;
        const int oc = e >> 8, icp = e & 255;
        const float4 a = *(const float4*)(W + ((size_t)oc * 512 + icp * 2) * 4);
        const float4 c = *(const float4*)(W + ((size_t)oc * 512 + icp * 2 + 1) * 4);
        v[0]=a.x; v[1]=c.x; v[2]=a.y; v[3]=c.y; v[4]=a.z; v[5]=c.z; v[6]=a.w; v[7]=c.w;
    }
    half8v hi, lo;
#pragma unroll
    for (int k = 0; k < 8; ++k) {
        const _Float16 h = (_Float16)v[k];
        hi[k] = h;
        lo[k] = (_Float16)(v[k] - (float)h);
    }
    *(half8v*)(dh + (size_t)e * 8) = hi;
    *(half8v*)(dl + (size_t)e * 8) = lo;
}

// ---------------------------------------------------------------------------
// conv0_store: raw conv0 (k=10,s=5) -> h0 f16 [b][512][6400] + GN stats.
// ---------------------------------------------------------------------------
__global__ __launch_bounds__(256) void conv0_store(
    const float* __restrict__ wav, const float* __restrict__ W0,
    _Float16* __restrict__ h0, float* __restrict__ stats)
{
    __shared__ float LW[5120];
    __shared__ float red[2][256];
    const int tid = threadIdx.x;
    for (int e = tid; e < 5120; e += 256) LW[e] = W0[e];

    const int b = blockIdx.y;
    const int t = blockIdx.x * 256 + tid;
    const bool valid = (t < 6399);
    float xv[10];
#pragma unroll
    for (int d = 0; d < 10; ++d) xv[d] = 0.f;
    if (valid) {
        const float* wp = wav + (size_t)b * 32000 + (size_t)t * 5;
#pragma unroll
        for (int d = 0; d < 10; ++d) xv[d] = wp[d];
    }
    __syncthreads();

    float lsum = 0.f, lsq = 0.f;
    _Float16* hb = h0 + (size_t)b * 512 * 6400;
    for (int oc = 0; oc < 512; ++oc) {
        float a = 0.f;
#pragma unroll
        for (int d = 0; d < 10; ++d) a += LW[oc * 10 + d] * xv[d];
        if (valid) {
            hb[(size_t)oc * 6400 + t] = (_Float16)a;
            lsum += a; lsq += a * a;
        }
    }
    red[0][tid] = lsum; red[1][tid] = lsq;
    __syncthreads();
    for (int s2 = 128; s2 > 0; s2 >>= 1) {
        if (tid < s2) { red[0][tid] += red[0][tid + s2]; red[1][tid] += red[1][tid + s2]; }
        __syncthreads();
    }
    if (tid == 0) {
        atomicAdd(&stats[2 * b], red[0][0]);
        atomicAdd(&stats[2 * b + 1], red[1][0]);
    }
}

// ---------------------------------------------------------------------------
// conv1_mfma: layer1 (K=8,S=4) from raw-f16 h0; applies GN0+ReLU inline in
// staging. MFMA f16, W compensated hi/lo (2 products). Output single f16
// pair-interleaved [b][256 pairs][1598][2] + GN1 stats.   (round-4 verbatim)
// ---------------------------------------------------------------------------
__global__ __launch_bounds__(256) void conv1_mfma(
    const _Float16* __restrict__ h0, const float* __restrict__ stats0,
    const float* __restrict__ g0, const float* __restrict__ b0,
    const _Float16* __restrict__ w1hi, const _Float16* __restrict__ w1lo,
    _Float16* __restrict__ oh, float* __restrict__ stats1)
{
    __shared__ _Float16 LWhi[2][64][40], LWlo[2][64][40];  // [k32l][oc][32+pad]
    __shared__ _Float16 LX[8][272];                        // [ic][sample]
    __shared__ float red[2][256];

    const int tid  = threadIdx.x;
    const int lane = tid & 63, wv = tid >> 6;
    const int m    = lane & 15, quad = lane >> 4;
    const int mt2  = wv >> 1, nt2 = wv & 1;
    const int b    = blockIdx.z;
    const int ocb  = blockIdx.y * 64;
    const int t0   = blockIdx.x * 64;
    const int Lout = 1598;

    const float invN0 = 1.f / (512.f * 6399.f);
    const float mu = stats0[2 * b] * invN0;
    const float var = stats0[2 * b + 1] * invN0 - mu * mu;
    const float rs = rsqrtf(var + 1e-5f);

    float4v acc[2][2];
#pragma unroll
    for (int i = 0; i < 2; ++i)
#pragma unroll
        for (int j = 0; j < 2; ++j) acc[i][j] = (float4v){0.f, 0.f, 0.f, 0.f};

    const _Float16* hb = h0 + (size_t)b * 512 * 6400;
    const int gbase = t0 * 4;

    for (int ic0 = 0; ic0 < 512; ic0 += 8) {
        __syncthreads();
        // --- stage W (pure copy from prepped hi/lo)
#pragma unroll
        for (int r = 0; r < 2; ++r) {
            const int e = tid + r * 256;
            const int k32l = e >> 8, oc = (e >> 2) & 63, q = e & 3;
            const size_t so = ((size_t)(ocb + oc) * 512 + ic0 + k32l * 4 + q) * 8;
            *(half8v*)&LWhi[k32l][oc][q * 8] = *(const half8v*)(w1hi + so);
            *(half8v*)&LWlo[k32l][oc][q * 8] = *(const half8v*)(w1lo + so);
        }
        // --- stage X: copy + affine + relu (272 16B-units)
        for (int e = tid; e < 272; e += 256) {
            const int ic = e / 34, u = e - ic * 34;
            const int gj = gbase + u * 8;
            const float sc = rs * g0[ic0 + ic];
            const float sh = b0[ic0 + ic] - mu * sc;
            const _Float16* src = hb + (size_t)(ic0 + ic) * 6400 + gj;
            half8v raw;
            if (gj + 7 < 6399) raw = *(const half8v*)src;
            else {
#pragma unroll
                for (int k = 0; k < 8; ++k) raw[k] = (gj + k < 6399) ? src[k] : (_Float16)0.f;
            }
            half8v nv;
#pragma unroll
            for (int k = 0; k < 8; ++k)
                nv[k] = (_Float16)fmaxf((float)raw[k] * sc + sh, 0.f);
            *(half8v*)&LX[ic][u * 8] = nv;
        }
        __syncthreads();
        // --- compute: 2 K-steps of 32
#pragma unroll
        for (int k32l = 0; k32l < 2; ++k32l) {
            half8v ahi[2], alo[2], bf[2];
#pragma unroll
            for (int i = 0; i < 2; ++i) {
                const int ocl = (mt2 * 2 + i) * 16 + m;
                ahi[i] = *(const half8v*)&LWhi[k32l][ocl][quad * 8];
                alo[i] = *(const half8v*)&LWlo[k32l][ocl][quad * 8];
            }
#pragma unroll
            for (int j = 0; j < 2; ++j) {
                const int tl = (nt2 * 2 + j) * 16 + m;
                const int icl = k32l * 4 + quad;
                const half4v x0 = *(const half4v*)&LX[icl][tl * 4];
                const half4v x1 = *(const half4v*)&LX[icl][tl * 4 + 4];
                bf[j] = __builtin_shufflevector(x0, x1, 0, 1, 2, 3, 4, 5, 6, 7);
            }
#pragma unroll
            for (int i = 0; i < 2; ++i)
#pragma unroll
                for (int j = 0; j < 2; ++j) {
                    acc[i][j] = __builtin_amdgcn_mfma_f32_16x16x32_f16(ahi[i], bf[j], acc[i][j], 0, 0, 0);
                    acc[i][j] = __builtin_amdgcn_mfma_f32_16x16x32_f16(alo[i], bf[j], acc[i][j], 0, 0, 0);
                }
        }
    }

    // --- epilogue: pack f16 pairs + stats
    float lsum = 0.f, lsq = 0.f;
    uint* ohU = (uint*)oh;
#pragma unroll
    for (int i = 0; i < 2; ++i) {
        const int ocb2 = ocb + (mt2 * 2 + i) * 16 + quad * 4;
#pragma unroll
        for (int j = 0; j < 2; ++j) {
            const int t = t0 + (nt2 * 2 + j) * 16 + m;
            if (t < Lout) {
#pragma unroll
                for (int pr = 0; pr < 2; ++pr) {
                    const float v0 = acc[i][j][pr * 2], v1 = acc[i][j][pr * 2 + 1];
                    union { uint u; _Float16 h[2]; } pk;
                    pk.h[0] = (_Float16)v0; pk.h[1] = (_Float16)v1;
                    const uint p = (uint)((ocb2 >> 1) + pr);
                    ohU[((size_t)(b * 256 + p)) * Lout + t] = pk.u;
                    lsum += v0 + v1; lsq += v0 * v0 + v1 * v1;
                }
            }
        }
    }
    __syncthreads();
    red[0][tid] = lsum; red[1][tid] = lsq;
    __syncthreads();
    for (int s2 = 128; s2 > 0; s2 >>= 1) {
        if (tid < s2) { red[0][tid] += red[0][tid + s2]; red[1][tid] += red[1][tid + s2]; }
        __syncthreads();
    }
    if (tid == 0) {
        atomicAdd(&stats1[2 * b], red[0][0]);
        atomicAdd(&stats1[2 * b + 1], red[1][0]);
    }
}

// ---------------------------------------------------------------------------
// conv_mfma: layers 2-4 (K=4,S=2). Input single f16 pair-interleaved.
// W prepped hi/lo (2 MFMAs). PAIRED: f16 pair-interleaved out; else fp32.
// (round-4 verbatim)
// ---------------------------------------------------------------------------
template <bool PAIRED>
__global__ __launch_bounds__(256) void conv_mfma(
    const _Float16* __restrict__ x,
    const _Float16* __restrict__ whi, const _Float16* __restrict__ wlo,
    _Float16* __restrict__ oh, float* __restrict__ oplain,
    float* __restrict__ stats, int Lin, int Lout)
{
    __shared__ _Float16 LWhi[2][64][40], LWlo[2][64][40];
    __shared__ _Float16 LX[8][272];
    __shared__ float red[2][256];

    const int tid  = threadIdx.x;
    const int lane = tid & 63, wv = tid >> 6;
    const int m    = lane & 15, quad = lane >> 4;
    const int mt2  = wv >> 1, nt2 = wv & 1;
    const int b    = blockIdx.z;
    const int ocb  = blockIdx.y * 64;
    const int t0   = blockIdx.x * 64;

    float4v acc[2][2];
#pragma unroll
    for (int i = 0; i < 2; ++i)
#pragma unroll
        for (int j = 0; j < 2; ++j) acc[i][j] = (float4v){0.f, 0.f, 0.f, 0.f};

    const int lim = (Lin - t0 * 2) * 2;

    for (int ic0 = 0; ic0 < 512; ic0 += 16) {
        __syncthreads();
        // --- stage W (copy)
#pragma unroll
        for (int r = 0; r < 2; ++r) {
            const int e = tid + r * 256;
            const int k32l = e >> 8, oc = (e >> 2) & 63, q = e & 3;
            const size_t so = ((size_t)(ocb + oc) * 256 + (ic0 >> 1) + k32l * 4 + q) * 8;
            *(half8v*)&LWhi[k32l][oc][q * 8] = *(const half8v*)(whi + so);
            *(half8v*)&LWlo[k32l][oc][q * 8] = *(const half8v*)(wlo + so);
        }
        // --- stage X (copy, 272 16B-units)
        for (int e = tid; e < 272; e += 256) {
            const int pl = e / 34, u = e - pl * 34;
            const _Float16* src = x + ((size_t)(b * 256 + (ic0 >> 1) + pl)) * ((size_t)Lin * 2)
                                   + (size_t)t0 * 4 + (size_t)u * 8;
            half8v val;
            if (u * 8 + 7 < lim) val = *(const half8v*)src;
            else {
#pragma unroll
                for (int k = 0; k < 8; ++k) val[k] = (u * 8 + k < lim) ? src[k] : (_Float16)0.f;
            }
            *(half8v*)&LX[pl][u * 8] = val;
        }
        __syncthreads();
        // --- compute
#pragma unroll
        for (int k32l = 0; k32l < 2; ++k32l) {
            half8v ahi[2], alo[2], bf[2];
#pragma unroll
            for (int i = 0; i < 2; ++i) {
                const int ocl = (mt2 * 2 + i) * 16 + m;
                ahi[i] = *(const half8v*)&LWhi[k32l][ocl][quad * 8];
                alo[i] = *(const half8v*)&LWlo[k32l][ocl][quad * 8];
            }
#pragma unroll
            for (int j = 0; j < 2; ++j) {
                const int tl = (nt2 * 2 + j) * 16 + m;
                const int pl = k32l * 4 + quad;
                const half4v x0 = *(const half4v*)&LX[pl][tl * 4];
                const half4v x1 = *(const half4v*)&LX[pl][tl * 4 + 4];
                bf[j] = __builtin_shufflevector(x0, x1, 0, 1, 2, 3, 4, 5, 6, 7);
            }
#pragma unroll
            for (int i = 0; i < 2; ++i)
#pragma unroll
                for (int j = 0; j < 2; ++j) {
                    acc[i][j] = __builtin_amdgcn_mfma_f32_16x16x32_f16(ahi[i], bf[j], acc[i][j], 0, 0, 0);
                    acc[i][j] = __builtin_amdgcn_mfma_f32_16x16x32_f16(alo[i], bf[j], acc[i][j], 0, 0, 0);
                }
        }
    }

    // --- epilogue
    float lsum = 0.f, lsq = 0.f;
    uint* ohU = (uint*)oh;
#pragma unroll
    for (int i = 0; i < 2; ++i) {
        const int ocb2 = ocb + (mt2 * 2 + i) * 16 + quad * 4;
#pragma unroll
        for (int j = 0; j < 2; ++j) {
            const int t = t0 + (nt2 * 2 + j) * 16 + m;
            if (t < Lout) {
                if (PAIRED) {
#pragma unroll
                    for (int pr = 0; pr < 2; ++pr) {
                        const float v0 = acc[i][j][pr * 2], v1 = acc[i][j][pr * 2 + 1];
                        union { uint u; _Float16 h[2]; } pk;
                        pk.h[0] = (_Float16)v0; pk.h[1] = (_Float16)v1;
                        const uint p = (uint)((ocb2 >> 1) + pr);
                        ohU[((size_t)(b * 256 + p)) * Lout + t] = pk.u;
                        lsum += v0 + v1; lsq += v0 * v0 + v1 * v1;
                    }
                } else {
#pragma unroll
                    for (int r = 0; r < 4; ++r) {
                        const float v = acc[i][j][r];
                        oplain[((size_t)(b * 512 + ocb2 + r)) * Lout + t] = v;
                        lsum += v; lsq += v * v;
                    }
                }
            }
        }
    }
    __syncthreads();
    red[0][tid] = lsum; red[1][tid] = lsq;
    __syncthreads();
    for (int s2 = 128; s2 > 0; s2 >>= 1) {
        if (tid < s2) { red[0][tid] += red[0][tid + s2]; red[1][tid] += red[1][tid + s2]; }
        __syncthreads();
    }
    if (tid == 0) {
        atomicAdd(&stats[2 * b], red[0][0]);
        atomicAdd(&stats[2 * b + 1], red[1][0]);
    }
}

// ---------------------------------------------------------------------------
// norm_pair: GN(1grp)+affine+ReLU in place on pair-interleaved f16.
// ---------------------------------------------------------------------------
__global__ __launch_bounds__(256) void norm_pair(
    uint* __restrict__ h, const float* __restrict__ stats,
    const float* __restrict__ gamma, const float* __restrict__ beta,
    int L, float invN)
{
    const int row = blockIdx.y;
    const int b = row >> 8, p = row & 255;
    const int t = blockIdx.x * 256 + threadIdx.x;
    if (t >= L) return;
    const int c0 = 2 * p, c1 = 2 * p + 1;
    const float mu = stats[2 * b] * invN;
    const float var = stats[2 * b + 1] * invN - mu * mu;
    const float rs = rsqrtf(var + 1e-5f);
    const float sc0 = rs * gamma[c0], sh0 = beta[c0] - mu * sc0;
    const float sc1 = rs * gamma[c1], sh1 = beta[c1] - mu * sc1;
    const size_t idx = (size_t)row * L + t;
    union { uint u; _Float16 h2[2]; } pk;
    pk.u = h[idx];
    const float n0 = fmaxf((float)pk.h2[0] * sc0 + sh0, 0.f);
    const float n1 = fmaxf((float)pk.h2[1] * sc1 + sh1, 0.f);
    pk.h2[0] = (_Float16)n0; pk.h2[1] = (_Float16)n1;
    h[idx] = pk.u;
}

// ---------------------------------------------------------------------------
// norm_feat: GN+affine+ReLU on plain fp32 features, in place.
// ---------------------------------------------------------------------------
__global__ __launch_bounds__(256) void norm_feat(
    float* __restrict__ h, const float* __restrict__ stats,
    const float* __restrict__ gamma, const float* __restrict__ beta,
    int L, float invN)
{
    const int row = blockIdx.y;
    const int b = row >> 9, oc = row & 511;
    const int t = blockIdx.x * 256 + threadIdx.x;
    if (t >= L) return;
    const float mu = stats[2 * b] * invN;
    const float var = stats[2 * b + 1] * invN - mu * mu;
    const float rs = rsqrtf(var + 1e-5f);
    const float sc = rs * gamma[oc];
    const float sh = beta[oc] - mu * sc;
    const size_t i = (size_t)row * L + t;
    const float v = h[i] * sc + sh;
    h[i] = v > 0.f ? v : 0.f;
}

// ---------------------------------------------------------------------------
// aa_kernel: row squared-norms of features.
// ---------------------------------------------------------------------------
__global__ __launch_bounds__(256) void aa_kernel(
    const float* __restrict__ fX, const float* __restrict__ fY,
    float* __restrict__ aaX, float* __restrict__ aaY)
{
    const int wave = threadIdx.x >> 6, lane = threadIdx.x & 63;
    const int R = blockIdx.x * 4 + wave;
    const float* f = (R < 8192) ? fX : fY;
    const int r = R & 8191;
    const float* row = f + (size_t)r * 198;
    float s = 0.f;
#pragma unroll
    for (int k = 0; k < 4; ++k) {
        const int j = lane + 64 * k;
        if (j < 198) { const float v = row[j]; s += v * v; }
    }
#pragma unroll
    for (int off = 32; off > 0; off >>= 1) s += __shfl_xor(s, off);
    if (lane == 0) ((R < 8192) ? aaX : aaY)[r] = s;
}

// ---------------------------------------------------------------------------
// cost_kernel: M = f16( min(50 * max(aa[n]+bb[m]-2<p,q>, 0), 65000) )
//            = 100 * C   where C = 0.5*max(aa+bb-2ab, 0).
// sink_update uses arg = 400*src - 4*M = 400*(src - C).
// ---------------------------------------------------------------------------
__global__ __launch_bounds__(256) void cost_kernel(
    const float* __restrict__ fX, const float* __restrict__ fY,
    const float* __restrict__ aaX, const float* __restrict__ aaY,
    _Float16* __restrict__ Cxy, _Float16* __restrict__ Cxx,
    _Float16* __restrict__ Cyy, _Float16* __restrict__ CTxy)
{
    const int z = blockIdx.z;
    const int mat = z >> 4, b = z & 15;
    const float *P, *Q, *aP, *aQ;
    _Float16 *Cm, *CT = nullptr;
    if (mat == 0) { P = fX; Q = fY; aP = aaX; aQ = aaY; Cm = Cxy; CT = CTxy; }
    else if (mat == 1) { P = fX; Q = fX; aP = aaX; aQ = aaX; Cm = Cxx; }
    else { P = fY; Q = fY; aP = aaY; aQ = aaY; Cm = Cyy; }

    const int n0 = blockIdx.x * 32, m0 = blockIdx.y * 32;
    __shared__ float LP[32][201], LQ[32][201];
    const int tid = threadIdx.x;
    for (int e = tid; e < 32 * 198; e += 256) {
        const int r = e / 198, d = e % 198;
        LP[r][d] = P[((size_t)b * 512 + n0 + r) * 198 + d];
        LQ[r][d] = Q[((size_t)b * 512 + m0 + r) * 198 + d];
    }
    __syncthreads();

    const int tx = tid & 31, ty = tid >> 5;
    float dot[4] = {0.f, 0.f, 0.f, 0.f};
    for (int d = 0; d < 198; ++d) {
        const float qv = LQ[tx][d];
#pragma unroll
        for (int q = 0; q < 4; ++q) dot[q] += LP[ty + 8 * q][d] * qv;
    }
    const int mm = m0 + tx;
    const float bbm = aQ[b * 512 + mm];
#pragma unroll
    for (int q = 0; q < 4; ++q) {
        const int n = n0 + ty + 8 * q;
        float c = 50.f * fmaxf(aP[b * 512 + n] + bbm - 2.f * dot[q], 0.f);  // == 100*C
        c = fminf(c, 65000.f);
        const _Float16 ch = (_Float16)c;
        Cm[((size_t)b * 512 + n) * 512 + mm] = ch;
        if (CT) CT[((size_t)b * 512 + mm) * 512 + n] = ch;
    }
}

// ---------------------------------------------------------------------------
// sink_update: dst[i] = eps*log512 - eps*LSE_j( 400*src[j] - 4*M100[i,j] )
// grid (32, 48); 4 waves/block, 4 rows/wave; src vector hoisted to registers.
// ---------------------------------------------------------------------------
__global__ __launch_bounds__(256) void sink_update(
    float* __restrict__ dst, const float* __restrict__ src,
    const _Float16* __restrict__ M0, const _Float16* __restrict__ M1,
    const _Float16* __restrict__ M2)
{
    const int p = blockIdx.y;
    const int mat = p >> 4, b = p & 15;
    const _Float16* M = (mat == 0) ? M0 : ((mat == 1) ? M1 : M2);
    const float* sp = src + (size_t)p * 512;
    __shared__ float sf[512];
    const int tid = threadIdx.x;
    sf[tid] = sp[tid] * INV_EPS_SINK;
    sf[tid + 256] = sp[tid + 256] * INV_EPS_SINK;
    __syncthreads();

    const int wave = tid >> 6, lane = tid & 63;
    float s8[8];
    {
        const float4 sa = *(const float4*)&sf[lane * 8];
        const float4 sb = *(const float4*)&sf[lane * 8 + 4];
        s8[0]=sa.x; s8[1]=sa.y; s8[2]=sa.z; s8[3]=sa.w;
        s8[4]=sb.x; s8[5]=sb.y; s8[6]=sb.z; s8[7]=sb.w;
    }

#pragma unroll
    for (int rr = 0; rr < 4; ++rr) {
        const int i = blockIdx.x * 16 + wave * 4 + rr;
        const half8v rv = *(const half8v*)(M + ((size_t)b * 512 + i) * 512 + lane * 8);
        float a8[8];
#pragma unroll
        for (int k = 0; k < 8; ++k) a8[k] = fmaf(-4.f, (float)rv[k], s8[k]);
        float mx = a8[0];
#pragma unroll
        for (int k = 1; k < 8; ++k) mx = fmaxf(mx, a8[k]);
        float ss = 0.f;
#pragma unroll
        for (int k = 0; k < 8; ++k) ss += __expf(a8[k] - mx);
#pragma unroll
        for (int off = 32; off > 0; off >>= 1) {
            const float om = __shfl_xor(mx, off);
            const float os = __shfl_xor(ss, off);
            const float nm = fmaxf(mx, om);
            ss = ss * __expf(mx - nm) + os * __expf(om - nm);
            mx = nm;
        }
        if (lane == 0)
            dst[(size_t)p * 512 + i] = EPS_LOG512 - EPS_SINK * (mx + logf(ss));
    }
}

// ---------------------------------------------------------------------------
__global__ __launch_bounds__(256) void final_kernel(
    const float* __restrict__ f, const float* __restrict__ g,
    float* __restrict__ out)
{
    const int b = blockIdx.x, tid = threadIdx.x;
    __shared__ float red[256];
    float a = 0.f;
    for (int n = tid; n < 512; n += 256) {
        const float xy = f[(0 * 16 + b) * 512 + n] + g[(0 * 16 + b) * 512 + n];
        const float xx = f[(1 * 16 + b) * 512 + n] + g[(1 * 16 + b) * 512 + n];
        const float yy = f[(2 * 16 + b) * 512 + n] + g[(2 * 16 + b) * 512 + n];
        a += xy - 0.5f * (xx + yy);
    }
    red[tid] = a;
    __syncthreads();
    for (int s2 = 128; s2 > 0; s2 >>= 1) {
        if (tid < s2) red[tid] += red[tid + s2];
        __syncthreads();
    }
    if (tid == 0) out[b] = red[0] * (1.0f / 512.0f);
}

// ---------------------------------------------------------------------------
extern "C" void kernel_launch(void* const* d_in, const int* in_sizes, int n_in,
                              void* d_out, int out_size, void* d_ws, size_t ws_size,
                              hipStream_t stream)
{
    (void)in_sizes; (void)n_in; (void)out_size; (void)ws_size;
    char* ws = (char*)d_ws;
    const float* yhat = (const float*)d_in[0];
    const float* ysig = (const float*)d_in[1];
    const float* Wl[5]; const float* gl[5]; const float* bl[5];
    for (int i = 0; i < 5; ++i) {
        Wl[i] = (const float*)d_in[2 + 3 * i];
        gl[i] = (const float*)d_in[3 + 3 * i];
        bl[i] = (const float*)d_in[4 + 3 * i];
    }
    float* out = (float*)d_out;
    float* statsA = (float*)(ws + O_STATS);

    _Float16* w1hi = (_Float16*)(ws + O_W1HI); _Float16* w1lo = (_Float16*)(ws + O_W1LO);
    _Float16* w2hi = (_Float16*)(ws + O_W2HI); _Float16* w2lo = (_Float16*)(ws + O_W2LO);
    _Float16* w3hi = (_Float16*)(ws + O_W3HI); _Float16* w3lo = (_Float16*)(ws + O_W3LO);
    _Float16* w4hi = (_Float16*)(ws + O_W4HI); _Float16* w4lo = (_Float16*)(ws + O_W4LO);
    _Float16* h0 = (_Float16*)(ws + O_H0);
    _Float16* h1 = (_Float16*)(ws + O_H1);
    _Float16* h2 = (_Float16*)(ws + O_H2);
    _Float16* h3 = (_Float16*)(ws + O_H3);

    hipMemsetAsync(statsA, 0, 512 * sizeof(float), stream);
    prep_w<<<dim3(1024, 4), 256, 0, stream>>>(Wl[1], Wl[2], Wl[3], Wl[4],
        w1hi, w1lo, w2hi, w2lo, w3hi, w3lo, w4hi, w4lo);

    for (int s = 0; s < 2; ++s) {
        const float* wav = (s == 0) ? yhat : ysig;
        float* st = statsA + (size_t)s * 160;
        float* ft = (float*)(ws + ((s == 0) ? O_FEATX : O_FEATY));

        conv0_store<<<dim3(25, 16), 256, 0, stream>>>(wav, Wl[0], h0, st);

        conv1_mfma<<<dim3(25, 8, 16), 256, 0, stream>>>(
            h0, st, gl[0], bl[0], w1hi, w1lo, h1, st + 32);
        norm_pair<<<dim3(7, 4096), 256, 0, stream>>>(
            (uint*)h1, st + 32, gl[1], bl[1], 1598, 1.f / (512.f * 1598.f));

        conv_mfma<true><<<dim3(13, 8, 16), 256, 0, stream>>>(
            h1, w2hi, w2lo, h2, nullptr, st + 64, 1598, 798);
        norm_pair<<<dim3(4, 4096), 256, 0, stream>>>(
            (uint*)h2, st + 64, gl[2], bl[2], 798, 1.f / (512.f * 798.f));

        conv_mfma<true><<<dim3(7, 8, 16), 256, 0, stream>>>(
            h2, w3hi, w3lo, h3, nullptr, st + 96, 798, 398);
        norm_pair<<<dim3(2, 4096), 256, 0, stream>>>(
            (uint*)h3, st + 96, gl[3], bl[3], 398, 1.f / (512.f * 398.f));

        conv_mfma<false><<<dim3(4, 8, 16), 256, 0, stream>>>(
            h3, w4hi, w4lo, nullptr, ft, st + 128, 398, 198);
        norm_feat<<<dim3(1, 8192), 256, 0, stream>>>(
            ft, st + 128, gl[4], bl[4], 198, 1.f / (512.f * 198.f));
    }

    float* featX = (float*)(ws + O_FEATX);
    float* featY = (float*)(ws + O_FEATY);
    aa_kernel<<<4096, 256, 0, stream>>>(featX, featY, (float*)(ws + O_AAX), (float*)(ws + O_AAY));
    cost_kernel<<<dim3(16, 16, 48), 256, 0, stream>>>(
        featX, featY, (float*)(ws + O_AAX), (float*)(ws + O_AAY),
        (_Float16*)(ws + O_CXY), (_Float16*)(ws + O_CXX), (_Float16*)(ws + O_CYY),
        (_Float16*)(ws + O_CTXY));

    hipMemsetAsync(ws + O_F, 0, 2 * 24576 * sizeof(float), stream);

    for (int it = 0; it < 50; ++it) {
        sink_update<<<dim3(32, 48), 256, 0, stream>>>(
            (float*)(ws + O_G), (float*)(ws + O_F),
            (_Float16*)(ws + O_CTXY), (_Float16*)(ws + O_CXX), (_Float16*)(ws + O_CYY));
        sink_update<<<dim3(32, 48), 256, 0, stream>>>(
            (float*)(ws + O_F), (float*)(ws + O_G),
            (_Float16*)(ws + O_CXY), (_Float16*)(ws + O_CXX), (_Float16*)(ws + O_CYY));
    }

    final_kernel<<<16, 256, 0, stream>>>((float*)(ws + O_F), (float*)(ws + O_G), out);
}